// Round 15
// baseline (253.382 us; speedup 1.0000x reference)
//
#include <hip/hip_runtime.h>
#include <hip/hip_bf16.h>
#include <math.h>

typedef short bf16x8 __attribute__((ext_vector_type(8)));
typedef float f32x4  __attribute__((ext_vector_type(4)));

#define GLOBAL_AS __attribute__((address_space(1)))
#define LDS_AS    __attribute__((address_space(3)))

__device__ __forceinline__ void async16(const void* g, void* l) {
  __builtin_amdgcn_global_load_lds((GLOBAL_AS void*)(g), (LDS_AS void*)(l), 16, 0, 0);
}

__device__ __forceinline__ unsigned short f2bf(float f){
  union { float f; unsigned u; } x; x.f = f;
  return (unsigned short)((x.u + 0x7fffu + ((x.u >> 16) & 1u)) >> 16);
}
__device__ __forceinline__ float bf2f(short s){
  union { unsigned u; float f; } x; x.u = ((unsigned)(unsigned short)s) << 16;
  return x.f;
}
__device__ __forceinline__ float gelu_f(float x){
  return 0.5f*x*(1.f+erff(x*0.70710678118654752f));
}

// ---------------- LayerNorm -> bf16 out ------------------------------------
__global__ __launch_bounds__(256) void ln_bf16(const float* __restrict__ in,
    const float* __restrict__ gg, const float* __restrict__ bb, short* __restrict__ out)
{
  const int row = blockIdx.x;
  const int tid = threadIdx.x;
  const float4 v = reinterpret_cast<const float4*>(in + (size_t)row*1024)[tid];
  float s  = v.x+v.y+v.z+v.w;
  float sq = v.x*v.x+v.y*v.y+v.z*v.z+v.w*v.w;
  #pragma unroll
  for (int off=32; off; off>>=1){ s += __shfl_xor(s,off); sq += __shfl_xor(sq,off); }
  __shared__ float ss[4], qs[4];
  const int wid = tid>>6, lane = tid&63;
  if (lane==0){ ss[wid]=s; qs[wid]=sq; }
  __syncthreads();
  s  = ss[0]+ss[1]+ss[2]+ss[3];
  sq = qs[0]+qs[1]+qs[2]+qs[3];
  const float mu  = s * (1.f/1024.f);
  const float var = sq*(1.f/1024.f) - mu*mu;
  const float rs  = rsqrtf(var + 1e-5f);
  const float4 g4 = reinterpret_cast<const float4*>(gg)[tid];
  const float4 b4 = reinterpret_cast<const float4*>(bb)[tid];
  ushort4 o;
  o.x = f2bf((v.x-mu)*rs*g4.x+b4.x);
  o.y = f2bf((v.y-mu)*rs*g4.y+b4.y);
  o.z = f2bf((v.z-mu)*rs*g4.z+b4.z);
  o.w = f2bf((v.w-mu)*rs*g4.w+b4.w);
  *reinterpret_cast<ushort4*>(out + (size_t)row*1024 + tid*4) = o;
}

// ------------- fused weight prep: all transposes in 1 launch ----------------
__device__ __forceinline__ void conv_body(const float* __restrict__ in,
    short* __restrict__ out, int K, int N, const float* __restrict__ add, int addN,
    int bx, int by)
{
  __shared__ float tile[32][33];
  const int n0 = bx*32, k0 = by*32;
  const int r = threadIdx.x >> 3, c4 = (threadIdx.x & 7)*4;
  float4 v = *reinterpret_cast<const float4*>(&in[(size_t)(k0+r)*N + n0 + c4]);
  if (add && (n0 + c4) < addN) {
    const float* ap = &add[(size_t)(k0+r)*addN + n0 + c4];
    v.x += ap[0]; v.y += ap[1]; v.z += ap[2]; v.w += ap[3];
  }
  tile[r][c4+0]=v.x; tile[r][c4+1]=v.y; tile[r][c4+2]=v.z; tile[r][c4+3]=v.w;
  __syncthreads();
  ushort4 o;
  o.x = f2bf(tile[c4+0][r]); o.y = f2bf(tile[c4+1][r]);
  o.z = f2bf(tile[c4+2][r]); o.w = f2bf(tile[c4+3][r]);
  *reinterpret_cast<ushort4*>(&out[(size_t)(n0+r)*K + k0 + c4]) = o;
}

__global__ __launch_bounds__(256) void prep_weights(
    const float* __restrict__ W_qkv, const float* __restrict__ W_O,
    const float* __restrict__ W_ug,  const float* __restrict__ B_w,
    const float* __restrict__ C_w,   const float* __restrict__ W1,
    const float* __restrict__ W2,
    short* __restrict__ wT_qkv, short* __restrict__ wT_o,
    short* __restrict__ wT_ug,  short* __restrict__ wT_c,
    short* __restrict__ wT_1,   short* __restrict__ wT_2)
{
  const int bid = blockIdx.x;
  if (bid < 3072) {
    conv_body(W_qkv, wT_qkv, 1024, 3072, nullptr, 0, bid % 96, bid / 96);
  } else if (bid < 4224) {
    const int j = bid - 3072;
    conv_body(W_ug, wT_ug, 1024, 1152, B_w, 128, j % 36, j / 36);
  } else if (bid < 5248) {
    const int j = bid - 4224;
    conv_body(W_O, wT_o, 1024, 1024, nullptr, 0, j % 32, j / 32);
  } else if (bid < 5376) {
    const int j = bid - 5248;
    conv_body(C_w, wT_c, 128, 1024, nullptr, 0, j % 32, j / 32);
  } else if (bid < 9472) {
    const int j = bid - 5376;
    conv_body(W1, wT_1, 1024, 4096, nullptr, 0, j % 128, j / 128);
  } else {
    const int j = bid - 9472;
    conv_body(W2, wT_2, 4096, 1024, nullptr, 0, j % 32, j / 32);
  }
}

// ======= 128x128 tile, BK=32, 4 waves, 2x16KB LDS -> 4-5 blocks/CU ==========
// Swizzle: blk ^ ((row>>1)&3)  (R3-verified, 0 bank conflicts at BK=32).
// EPI: 0 = plain bf16 out; 2 = bias+gelu bf16 out.
template<int EPI>
__global__ __launch_bounds__(256) void gemm32(
    const short* __restrict__ A, const short* __restrict__ Bt,
    const float* __restrict__ bias, short* __restrict__ Cout,
    int M, int N, int K)
{
  constexpr int ABY = 8192;        // 128 rows * 32 k * 2B
  constexpr int STR = ABY + 8192;  // one buffer (A+B) = 16KB
  extern __shared__ char lds[];    // 2 * STR = 32KB
  const int tid = threadIdx.x;
  const int ln = tid & 63, w = tid >> 6;
  const int wr = w >> 1, wc = w & 1;
  const int lane15 = ln & 15, lgrp = ln >> 4;

  const int gx = gridDim.x;
  const int nwg = gx * gridDim.y;
  int id = blockIdx.y * gx + blockIdx.x;
  if ((nwg & 7) == 0) { const int cpx = nwg >> 3; id = (id & 7) * cpx + (id >> 3); }
  const int m0 = (id / gx) * 128, n0 = (id % gx) * 128;

  const int NT = K >> 5;

  f32x4 acc[4][4];
  #pragma unroll
  for (int i=0;i<4;i++)
    #pragma unroll
    for (int j=0;j<4;j++) acc[i][j] = (f32x4){0.f,0.f,0.f,0.f};

  // p in {0,1}: 512 slots per matrix across 2 calls; 1 A + 1 B load per thread
  #define STG32(k0_, bufA_, bufB_, p_) { \
    const int slot = (p_)*256 + tid; \
    const int row = slot >> 2, blk = slot & 3; \
    const int sblk = blk ^ ((row >> 1) & 3); \
    async16(A  + (size_t)(m0+row)*K + (k0_) + sblk*8, (bufA_) + slot*16); \
    async16(Bt + (size_t)(n0+row)*K + (k0_) + sblk*8, (bufB_) + slot*16); }

  {
    char* bA = lds, *bB = lds + ABY;
    STG32(0, bA, bB, 0); STG32(0, bA, bB, 1);
    if (NT > 1) { char* cA = lds + STR, *cB = cA + ABY; STG32(32, cA, cB, 0); }
    asm volatile("s_waitcnt vmcnt(0)" ::: "memory");
    __builtin_amdgcn_s_barrier();
    __builtin_amdgcn_sched_barrier(0);
  }

  for (int kt = 0; kt < NT; ++kt) {
    const int cur = kt & 1;
    char* rdA = lds + cur*STR;   char* rdB = rdA + ABY;
    char* wrA = lds + (cur^1)*STR; char* wrB = wrA + ABY;
    const int kn = (kt+1) << 5;

    bf16x8 bfr[4];
    #pragma unroll
    for (int ni = 0; ni < 4; ni++) {
      const int row = wc*64 + ni*16 + lane15;
      const int b = lgrp ^ ((row >> 1) & 3);
      bfr[ni] = *reinterpret_cast<const bf16x8*>(rdB + (row*4 + b)*16);
    }
    if (kt+1 < NT) STG32(kn, wrA, wrB, 1);
    #pragma unroll
    for (int mq = 0; mq < 2; ++mq) {
      bf16x8 af[2];
      #pragma unroll
      for (int mi = 0; mi < 2; mi++) {
        const int row = wr*64 + (mq*2+mi)*16 + lane15;
        const int b = lgrp ^ ((row >> 1) & 3);
        af[mi] = *reinterpret_cast<const bf16x8*>(rdA + (row*4 + b)*16);
      }
      #pragma unroll
      for (int mi = 0; mi < 2; mi++)
        #pragma unroll
        for (int ni = 0; ni < 4; ni++)
          acc[mq*2+mi][ni] = __builtin_amdgcn_mfma_f32_16x16x32_bf16(
              af[mi], bfr[ni], acc[mq*2+mi][ni], 0, 0, 0);
    }
    if (kt+1 < NT) {
      __builtin_amdgcn_s_barrier();
      if (kt+2 < NT) {
        STG32((kt+2) << 5, rdA, rdB, 0);
        asm volatile("s_waitcnt vmcnt(2)" ::: "memory");
      } else {
        asm volatile("s_waitcnt vmcnt(0)" ::: "memory");
      }
      __builtin_amdgcn_s_barrier();
      __builtin_amdgcn_sched_barrier(0);
    }
  }
  #undef STG32

  #pragma unroll
  for (int ni = 0; ni < 4; ni++) {
    const int col = n0 + wc*64 + ni*16 + lane15;
    const float bv = bias ? bias[col] : 0.f;
    #pragma unroll
    for (int mi = 0; mi < 4; mi++) {
      #pragma unroll
      for (int r = 0; r < 4; r++) {
        const int row = m0 + wr*64 + mi*16 + lgrp*4 + r;
        float v = acc[mi][ni][r] + bv;
        if (EPI == 2) v = gelu_f(v);
        Cout[(size_t)row*N + col] = (short)f2bf(v);
      }
    }
  }
}

// ====== BM x 128 tile (BM = MT*32), BK=64, 4 waves, counted-vmcnt pipeline ==
// EPI: 1 = UG split; 3 = RES fp32 in-place
template<int MT, int EPI>
__global__ __launch_bounds__(256) void gemm128(
    const short* __restrict__ A, const short* __restrict__ Bt,
    const float* __restrict__ bias,
    short* __restrict__ e_g,
    void* __restrict__ Cout, int M, int N, int K)
{
  constexpr int BM  = MT * 32;
  constexpr int ABY = BM * 128;
  constexpr int STR = ABY + 16384;
  constexpr int MPQ = MT / 2;
  extern __shared__ char lds[];
  const int tid = threadIdx.x;
  const int ln = tid & 63, w = tid >> 6;
  const int wr = w >> 1, wc = w & 1;
  const int lane15 = ln & 15, lgrp = ln >> 4;

  const int gx = gridDim.x;
  const int nwg = gx * gridDim.y;
  int id = blockIdx.y * gx + blockIdx.x;
  if ((nwg & 7) == 0) { const int cpx = nwg >> 3; id = (id & 7) * cpx + (id >> 3); }
  const int m0 = (id / gx) * BM, n0 = (id % gx) * 128;

  const int NT = K >> 6;

  f32x4 acc[MT][4];
  #pragma unroll
  for (int i=0;i<MT;i++)
    #pragma unroll
    for (int j=0;j<4;j++) acc[i][j] = (f32x4){0.f,0.f,0.f,0.f};

  #define STG(k0_, bufA_, bufB_, p_) { \
    const int slot = (p_)*256 + tid; \
    const int row = slot >> 3, blk = slot & 7; \
    const int sblk = blk ^ (row & 7); \
    if ((p_) < MT) async16(A + (size_t)(m0+row)*K + (k0_) + sblk*8, (bufA_) + slot*16); \
    async16(Bt + (size_t)(n0+row)*K + (k0_) + sblk*8, (bufB_) + slot*16); }

  {
    char* bA = lds, *bB = lds + ABY;
    STG(0, bA, bB, 0); STG(0, bA, bB, 1); STG(0, bA, bB, 2); STG(0, bA, bB, 3);
    if (NT > 1) { char* cA = lds + STR, *cB = cA + ABY; STG(64, cA, cB, 0); }
    asm volatile("s_waitcnt vmcnt(0)" ::: "memory");
    __builtin_amdgcn_s_barrier();
    __builtin_amdgcn_sched_barrier(0);
  }

  for (int kt = 0; kt < NT; ++kt) {
    const int cur = kt & 1;
    char* rdA = lds + cur*STR;   char* rdB = rdA + ABY;
    char* wrA = lds + (cur^1)*STR; char* wrB = wrA + ABY;
    const int kn = (kt+1) << 6;
    bf16x8 bfr[4][2];
    #pragma unroll
    for (int ni = 0; ni < 4; ni++) {
      const int row = wc*64 + ni*16 + lane15;
      #pragma unroll
      for (int ks = 0; ks < 2; ks++) {
        const int b = (ks*4 + lgrp) ^ (row & 7);
        bfr[ni][ks] = *reinterpret_cast<const bf16x8*>(rdB + (row*8 + b)*16);
      }
    }
    if (kt+1 < NT) STG(kn, wrA, wrB, 1);
    #pragma unroll
    for (int mq = 0; mq < 2; ++mq) {
      bf16x8 af[MPQ][2];
      #pragma unroll
      for (int mi = 0; mi < MPQ; mi++) {
        const int row = wr*(MT*16) + (mq*MPQ+mi)*16 + lane15;
        #pragma unroll
        for (int ks = 0; ks < 2; ks++) {
          const int b = (ks*4 + lgrp) ^ (row & 7);
          af[mi][ks] = *reinterpret_cast<const bf16x8*>(rdA + (row*8 + b)*16);
        }
      }
      if (kt+1 < NT) STG(kn, wrA, wrB, 2+mq);
      #pragma unroll
      for (int mi = 0; mi < MPQ; mi++)
        #pragma unroll
        for (int ni = 0; ni < 4; ni++)
          #pragma unroll
          for (int ks = 0; ks < 2; ks++)
            acc[mq*MPQ+mi][ni] = __builtin_amdgcn_mfma_f32_16x16x32_bf16(
                af[mi][ks], bfr[ni][ks], acc[mq*MPQ+mi][ni], 0, 0, 0);
    }
    if (kt+1 < NT) {
      __builtin_amdgcn_s_barrier();
      if (kt+2 < NT) {
        STG((kt+2) << 6, rdA, rdB, 0);
        asm volatile("s_waitcnt vmcnt(2)" ::: "memory");
      } else {
        asm volatile("s_waitcnt vmcnt(0)" ::: "memory");
      }
      __builtin_amdgcn_s_barrier();
      __builtin_amdgcn_sched_barrier(0);
    }
  }
  #undef STG

  #pragma unroll
  for (int ni = 0; ni < 4; ni++) {
    const int col = n0 + wc*64 + ni*16 + lane15;
    const float bv = bias ? bias[col] : 0.f;
    #pragma unroll
    for (int mi = 0; mi < MT; mi++) {
      #pragma unroll
      for (int r = 0; r < 4; r++) {
        const int row = m0 + wr*(MT*16) + mi*16 + lgrp*4 + r;
        float v = acc[mi][ni][r] + bv;
        if (EPI == 1) {
          if (col < 128) ((float*)Cout)[(size_t)row*128 + col] = v;
          else {
            const float gs = 1.f/(1.f+__expf(-v));
            e_g[(size_t)row*1024 + col - 128] = (short)f2bf(gs);
          }
        } else {
          float* o = (float*)Cout;
          o[(size_t)row*N + col] = v + o[(size_t)row*N + col];
        }
      }
    }
  }
}

// ====== Fused W_O + C_w combine: out = x + g*(attn@WO+bO) + (1-g)*(st@Cw) ===
__global__ __launch_bounds__(256) void wo_comb(
    const short* __restrict__ A1, const short* __restrict__ B1t,
    const short* __restrict__ A2, const short* __restrict__ B2t,
    const float* __restrict__ bias, const float* __restrict__ e_x,
    const short* __restrict__ e_g, float* __restrict__ Cout)
{
  constexpr int ABY = 8192;
  constexpr int STR = ABY + 16384;
  extern __shared__ char lds[];
  const int tid = threadIdx.x;
  const int ln = tid & 63, w = tid >> 6;
  const int wr = w >> 1, wc = w & 1;
  const int lane15 = ln & 15, lgrp = ln >> 4;
  const int K = 1024, N = 1024;

  const int gx = gridDim.x;
  const int nwg = gx * gridDim.y;
  int id = blockIdx.y * gx + blockIdx.x;
  if ((nwg & 7) == 0) { const int cpx = nwg >> 3; id = (id & 7) * cpx + (id >> 3); }
  const int m0 = (id / gx) * 64, n0 = (id % gx) * 128;

  f32x4 acc1[2][4], acc2[2][4];
  #pragma unroll
  for (int i=0;i<2;i++)
    #pragma unroll
    for (int j=0;j<4;j++){ acc1[i][j] = (f32x4){0.f,0.f,0.f,0.f}; acc2[i][j] = (f32x4){0.f,0.f,0.f,0.f}; }

  #define STGW(Asrc_, Bsrc_, AK_, k0_, bufA_, bufB_, p_) { \
    const int slot = (p_)*256 + tid; \
    const int row = slot >> 3, blk = slot & 7; \
    const int sblk = blk ^ (row & 7); \
    if ((p_) < 2) async16(Asrc_ + (size_t)(m0+row)*(AK_) + (k0_) + sblk*8, (bufA_) + slot*16); \
    async16(Bsrc_ + (size_t)(n0+row)*(AK_) + (k0_) + sblk*8, (bufB_) + slot*16); }

  {
    char* bA = lds, *bB = lds + ABY;
    STGW(A1, B1t, K, 0, bA, bB, 0); STGW(A1, B1t, K, 0, bA, bB, 1);
    STGW(A1, B1t, K, 0, bA, bB, 2); STGW(A1, B1t, K, 0, bA, bB, 3);
    { char* cA = lds + STR, *cB = cA + ABY; STGW(A1, B1t, K, 64, cA, cB, 0); }
    asm volatile("s_waitcnt vmcnt(0)" ::: "memory");
    __builtin_amdgcn_s_barrier();
    __builtin_amdgcn_sched_barrier(0);
  }

  const int NT = 16;
  for (int kt = 0; kt < NT; ++kt) {
    const int cur = kt & 1;
    char* rdA = lds + cur*STR;   char* rdB = rdA + ABY;
    char* wrA = lds + (cur^1)*STR; char* wrB = wrA + ABY;
    const int kn = (kt+1) << 6;
    bf16x8 bfr[4][2];
    #pragma unroll
    for (int ni = 0; ni < 4; ni++) {
      const int row = wc*64 + ni*16 + lane15;
      #pragma unroll
      for (int ks = 0; ks < 2; ks++) {
        const int b = (ks*4 + lgrp) ^ (row & 7);
        bfr[ni][ks] = *reinterpret_cast<const bf16x8*>(rdB + (row*8 + b)*16);
      }
    }
    if (kt+1 < NT) STGW(A1, B1t, K, kn, wrA, wrB, 1);
    #pragma unroll
    for (int mq = 0; mq < 2; ++mq) {
      bf16x8 af[2];
      {
        const int row = wr*32 + mq*16 + lane15;
        #pragma unroll
        for (int ks = 0; ks < 2; ks++) {
          const int b = (ks*4 + lgrp) ^ (row & 7);
          af[ks] = *reinterpret_cast<const bf16x8*>(rdA + (row*8 + b)*16);
        }
      }
      if (kt+1 < NT) STGW(A1, B1t, K, kn, wrA, wrB, 2+mq);
      #pragma unroll
      for (int ni = 0; ni < 4; ni++)
        #pragma unroll
        for (int ks = 0; ks < 2; ks++)
          acc1[mq][ni] = __builtin_amdgcn_mfma_f32_16x16x32_bf16(
              af[ks], bfr[ni][ks], acc1[mq][ni], 0, 0, 0);
    }
    if (kt+1 < NT) {
      __builtin_amdgcn_s_barrier();
      if (kt+2 < NT) {
        STGW(A1, B1t, K, (kt+2) << 6, rdA, rdB, 0);
        asm volatile("s_waitcnt vmcnt(2)" ::: "memory");
      } else {
        asm volatile("s_waitcnt vmcnt(0)" ::: "memory");
      }
      __builtin_amdgcn_s_barrier();
      __builtin_amdgcn_sched_barrier(0);
    }
  }

  __builtin_amdgcn_s_barrier();
  {
    char* bA0 = lds,       *bB0 = lds + ABY;
    char* bA1 = lds + STR, *bB1 = bA1 + ABY;
    STGW(A2, B2t, 128, 0,  bA0, bB0, 0); STGW(A2, B2t, 128, 0,  bA0, bB0, 1);
    STGW(A2, B2t, 128, 0,  bA0, bB0, 2); STGW(A2, B2t, 128, 0,  bA0, bB0, 3);
    STGW(A2, B2t, 128, 64, bA1, bB1, 0); STGW(A2, B2t, 128, 64, bA1, bB1, 1);
    STGW(A2, B2t, 128, 64, bA1, bB1, 2); STGW(A2, B2t, 128, 64, bA1, bB1, 3);
    asm volatile("s_waitcnt vmcnt(0)" ::: "memory");
    __builtin_amdgcn_s_barrier();
  }
  #pragma unroll
  for (int t2 = 0; t2 < 2; ++t2) {
    char* rdA = lds + t2*STR; char* rdB = rdA + ABY;
    bf16x8 bfr2[4][2];
    #pragma unroll
    for (int ni = 0; ni < 4; ni++) {
      const int brow = wc*64 + ni*16 + lane15;
      #pragma unroll
      for (int ks = 0; ks < 2; ks++) {
        const int b = (ks*4 + lgrp) ^ (brow & 7);
        bfr2[ni][ks] = *reinterpret_cast<const bf16x8*>(rdB + (brow*8 + b)*16);
      }
    }
    #pragma unroll
    for (int mi = 0; mi < 2; mi++) {
      bf16x8 af[2];
      const int row = wr*32 + mi*16 + lane15;
      #pragma unroll
      for (int ks = 0; ks < 2; ks++) {
        const int b = (ks*4 + lgrp) ^ (row & 7);
        af[ks] = *reinterpret_cast<const bf16x8*>(rdA + (row*8 + b)*16);
      }
      #pragma unroll
      for (int ni = 0; ni < 4; ni++)
        #pragma unroll
        for (int ks = 0; ks < 2; ks++)
          acc2[mi][ni] = __builtin_amdgcn_mfma_f32_16x16x32_bf16(af[ks], bfr2[ni][ks], acc2[mi][ni], 0, 0, 0);
    }
  }
  #undef STGW

  #pragma unroll
  for (int ni = 0; ni < 4; ni++) {
    const int col = n0 + wc*64 + ni*16 + lane15;
    const float bv = bias[col];
    #pragma unroll
    for (int mi = 0; mi < 2; mi++) {
      #pragma unroll
      for (int r = 0; r < 4; r++) {
        const int row = m0 + wr*32 + mi*16 + lgrp*4 + r;
        const float g = bf2f(e_g[(size_t)row*1024 + col]);
        Cout[(size_t)row*N + col] = e_x[(size_t)row*1024 + col]
            + g*(acc1[mi][ni][r] + bv) + (1.f-g)*acc2[mi][ni][r];
      }
    }
  }
}

// ---------------- Flash sliding-window attention (MFMA, bf16) ---------------
#define ATS 72
__global__ __launch_bounds__(256) void attn_mfma(const short* __restrict__ qkv,
                                                 short* __restrict__ attn_out)
{
  __shared__ short Qs[64*ATS];
  __shared__ short Ks[64*ATS];
  __shared__ short Vt[64*ATS];
  __shared__ short Ps[4][16*ATS];
  const int tid = threadIdx.x;
  const int ln = tid & 63, w = tid >> 6;
  const int qt0 = (blockIdx.x >> 4) * 64;
  const int h = blockIdx.x & 15;

  {
    const int jr = tid >> 3, d0 = (tid & 7) * 8;
    #pragma unroll
    for (int p = 0; p < 2; p++) {
      const int j = jr + p*32;
      const bf16x8 v = *reinterpret_cast<const bf16x8*>(&qkv[(size_t)(qt0 + j)*3072 + h*64 + d0]);
      const int blk = (d0 >> 3) ^ (j & 7);
      *reinterpret_cast<bf16x8*>(&Qs[j*ATS + blk*8]) = v;
    }
  }

  float mrow[4], lrow[4];
  f32x4 oacc[4];
  #pragma unroll
  for (int r=0;r<4;r++){ mrow[r] = -1e30f; lrow[r] = 0.f; }
  #pragma unroll
  for (int df=0;df<4;df++) oacc[df] = (f32x4){0.f,0.f,0.f,0.f};

  const int qrow_lane = w*16 + (ln>>4)*4;
  const int qtile = qt0 >> 6;
  const int cstart = (qtile >= 4) ? 0 : (4 - qtile);

  for (int c = cstart; c < 5; c++) {
    const int cs = qt0 - 256 + c*64;
    {
      const int jr = tid >> 3, d0 = (tid & 7) * 8;
      #pragma unroll
      for (int p = 0; p < 2; p++) {
        const int j = jr + p*32;
        const size_t krow = (size_t)(cs + j)*3072 + h*64;
        const bf16x8 kv = *reinterpret_cast<const bf16x8*>(&qkv[krow + 1024 + d0]);
        const int blk = (d0>>3) ^ (j & 7);
        *reinterpret_cast<bf16x8*>(&Ks[j*ATS + blk*8]) = kv;
        const bf16x8 vv = *reinterpret_cast<const bf16x8*>(&qkv[krow + 2048 + d0]);
        #pragma unroll
        for (int i = 0; i < 8; i++) {
          const int d = d0 + i;
          const int jb = (j >> 3) ^ ((d >> 3) & 7);
          Vt[d*ATS + jb*8 + (j & 7)] = ((const short*)&vv)[i];
        }
      }
    }
    __syncthreads();

    bf16x8 aq[2];
    #pragma unroll
    for (int ks=0; ks<2; ks++){
      const int row = w*16 + (ln & 15);
      const int b = (ks*4 + (ln>>4)) ^ (row & 7);
      aq[ks] = *reinterpret_cast<const bf16x8*>(&Qs[row*ATS + b*8]);
    }
    float sv[4][4];
    #pragma unroll
    for (int nf=0; nf<4; nf++){
      const int krow = nf*16 + (ln & 15);
      f32x4 s = (f32x4){0.f,0.f,0.f,0.f};
      #pragma unroll
      for (int ks=0; ks<2; ks++){
        const int b = (ks*4 + (ln>>4)) ^ (krow & 7);
        const bf16x8 bk = *reinterpret_cast<const bf16x8*>(&Ks[krow*ATS + b*8]);
        s = __builtin_amdgcn_mfma_f32_16x16x32_bf16(aq[ks], bk, s, 0, 0, 0);
      }
      const int k_abs = cs + nf*16 + (ln & 15);
      #pragma unroll
      for (int r=0;r<4;r++){
        const int t_abs = qt0 + qrow_lane + r;
        const bool valid = (k_abs <= t_abs) && (k_abs >= t_abs - 255);
        sv[nf][r] = valid ? s[r]*0.125f : -1e30f;
      }
    }
    float cm[4], alpha[4], rs[4];
    #pragma unroll
    for (int r=0;r<4;r++){
      cm[r] = fmaxf(fmaxf(sv[0][r],sv[1][r]), fmaxf(sv[2][r],sv[3][r]));
      #pragma unroll
      for (int off=1; off<16; off<<=1) cm[r] = fmaxf(cm[r], __shfl_xor(cm[r], off));
      const float mnew = fmaxf(mrow[r], cm[r]);
      alpha[r] = __expf(mrow[r] - mnew);
      mrow[r] = mnew;
      rs[r] = 0.f;
    }
    #pragma unroll
    for (int nf=0; nf<4; nf++){
      const int pcol = nf*16 + (ln & 15);
      #pragma unroll
      for (int r=0;r<4;r++){
        const float p = (sv[nf][r] <= -1e29f) ? 0.f : __expf(sv[nf][r] - mrow[r]);
        rs[r] += p;
        const int prow = (ln>>4)*4 + r;
        const int pb = (pcol>>3) ^ (prow & 7);
        Ps[w][prow*ATS + pb*8 + (pcol & 7)] = (short)f2bf(p);
      }
    }
    #pragma unroll
    for (int r=0;r<4;r++){
      #pragma unroll
      for (int off=1; off<16; off<<=1) rs[r] += __shfl_xor(rs[r], off);
      lrow[r] = lrow[r]*alpha[r] + rs[r];
      #pragma unroll
      for (int df=0; df<4; df++) oacc[df][r] *= alpha[r];
    }
    bf16x8 ap[2];
    #pragma unroll
    for (int ks=0; ks<2; ks++){
      const int prow = (ln & 15);
      const int b = (ks*4 + (ln>>4)) ^ (prow & 7);
      ap[ks] = *reinterpret_cast<const bf16x8*>(&Ps[w][prow*ATS + b*8]);
    }
    #pragma unroll
    for (int df=0; df<4; df++){
      const int vrow = df*16 + (ln & 15);
      #pragma unroll
      for (int ks=0; ks<2; ks++){
        const int b = (ks*4 + (ln>>4)) ^ ((vrow>>3) & 7);
        const bf16x8 bv = *reinterpret_cast<const bf16x8*>(&Vt[vrow*ATS + b*8]);
        oacc[df] = __builtin_amdgcn_mfma_f32_16x16x32_bf16(ap[ks], bv, oacc[df], 0, 0, 0);
      }
    }
    __syncthreads();
  }

  #pragma unroll
  for (int df=0; df<4; df++)
    #pragma unroll
    for (int r=0; r<4; r++){
      const int t = qt0 + qrow_lane + r;
      const int d = df*16 + (ln & 15);
      attn_out[(size_t)t*1024 + h*64 + d] = (short)f2bf(oacc[df][r] / lrow[r]);
    }
}

// ---------------- SSM scan as 16-tap convolution (compact drive) ------------
__global__ __launch_bounds__(256) void scan_kernel(const float* __restrict__ drive,
    const float* __restrict__ Aa, short* __restrict__ states)
{
  const int idx = blockIdx.x*256 + threadIdx.x;
  const int t = idx >> 7, s = idx & 127;
  const float a = Aa[s];
  float acc = 0.f, pw = 1.f;
  const int kmax = (t+1 < 16) ? (t+1) : 16;
  for (int k=0;k<kmax;k++){
    acc = fmaf(pw, drive[(size_t)(t-k)*128 + s], acc);
    pw *= a;
  }
  states[idx] = (short)f2bf(acc);
}

extern "C" void kernel_launch(void* const* d_in, const int* in_sizes, int n_in,
                              void* d_out, int out_size, void* d_ws, size_t ws_size,
                              hipStream_t stream)
{
  const float* x     = (const float*)d_in[0];
  const float* ln1_g = (const float*)d_in[1];
  const float* ln1_b = (const float*)d_in[2];
  const float* ln2_g = (const float*)d_in[3];
  const float* ln2_b = (const float*)d_in[4];
  const float* W_qkv = (const float*)d_in[5];
  const float* W_O   = (const float*)d_in[6];
  const float* b_O   = (const float*)d_in[7];
  const float* W_ug  = (const float*)d_in[8];
  const float* b_ug  = (const float*)d_in[9];
  const float* B_w   = (const float*)d_in[10];
  const float* A     = (const float*)d_in[11];
  const float* C_w   = (const float*)d_in[12];
  const float* W1    = (const float*)d_in[13];
  const float* b1    = (const float*)d_in[14];
  const float* W2    = (const float*)d_in[15];
  const float* b2    = (const float*)d_in[16];
  float* out = (float*)d_out;
  char* ws = (char*)d_ws;

  short* qkv_bf = (short*)(ws + 0);          // 24MB
  short* attn_bf= (short*)(ws + 25165824);   // 8MB
  short* xn_bf  = (short*)(ws + 33554432);   // 8MB (h aliases)
  short* g_bf   = (short*)(ws + 41943040);   // 8MB
  float* drive  = (float*)(ws + 50331648);   // 2MB
  short* st_bf  = (short*)(ws + 52428800);   // 1MB
  short* wT_qkv = (short*)(ws + 53542912);   // 6MB
  short* wT_o   = (short*)(ws + 59834368);   // 2MB
  short* wT_ug  = (short*)(ws + 61931520);   // 2.25MB
  short* wT_c   = (short*)(ws + 64290816);   // 0.25MB
  short* wT_1   = (short*)(ws + 64552960);   // 8MB
  short* wT_2   = (short*)(ws + 72941568);   // 8MB
  short* mid_bf = (short*)(ws + 0);          // 32MB alias (dead qkv+attn)
  short* h_bf   = xn_bf;

  static bool attr_done = false;
  if (!attr_done) {
    hipFuncSetAttribute((const void*)gemm32<0>, hipFuncAttributeMaxDynamicSharedMemorySize, 32768);
    hipFuncSetAttribute((const void*)gemm32<2>, hipFuncAttributeMaxDynamicSharedMemorySize, 32768);
    hipFuncSetAttribute((const void*)(gemm128<2,1>), hipFuncAttributeMaxDynamicSharedMemorySize, 49152);
    hipFuncSetAttribute((const void*)(gemm128<2,3>), hipFuncAttributeMaxDynamicSharedMemorySize, 49152);
    hipFuncSetAttribute((const void*)wo_comb, hipFuncAttributeMaxDynamicSharedMemorySize, 49152);
    attr_done = true;
  }

  prep_weights<<<13568, 256, 0, stream>>>(W_qkv, W_O, W_ug, B_w, C_w, W1, W2,
                                          wT_qkv, wT_o, wT_ug, wT_c, wT_1, wT_2);

  ln_bf16<<<4096, 256, 0, stream>>>(x, ln1_g, ln1_b, xn_bf);
  gemm32<0><<<dim3(24,32), 256, 32768, stream>>>(xn_bf, wT_qkv, nullptr, qkv_bf, 4096, 3072, 1024);
  attn_mfma<<<1024, 256, 0, stream>>>(qkv_bf, attn_bf);
  gemm128<2,1><<<dim3(9,64), 256, 49152, stream>>>(xn_bf, wT_ug, b_ug, g_bf, drive, 4096, 1152, 1024);
  scan_kernel<<<2048, 256, 0, stream>>>(drive, A, st_bf);
  wo_comb<<<dim3(8,64), 256, 49152, stream>>>(attn_bf, wT_o, st_bf, wT_c, b_O, x, g_bf, out);
  ln_bf16<<<4096, 256, 0, stream>>>(out, ln2_g, ln2_b, h_bf);
  gemm32<2><<<dim3(32,32), 256, 32768, stream>>>(h_bf, wT_1, b1, mid_bf, 4096, 4096, 1024);
  gemm128<2,3><<<dim3(8,64), 256, 49152, stream>>>(mid_bf, wT_2, b2, nullptr, out, 4096, 1024, 4096);
}

// Round 16
// 242.673 us; speedup vs baseline: 1.0441x; 1.0441x over previous
//
#include <hip/hip_runtime.h>
#include <hip/hip_bf16.h>
#include <math.h>

typedef short bf16x8 __attribute__((ext_vector_type(8)));
typedef float f32x4  __attribute__((ext_vector_type(4)));

#define GLOBAL_AS __attribute__((address_space(1)))
#define LDS_AS    __attribute__((address_space(3)))

__device__ __forceinline__ void async16(const void* g, void* l) {
  __builtin_amdgcn_global_load_lds((GLOBAL_AS void*)(g), (LDS_AS void*)(l), 16, 0, 0);
}

__device__ __forceinline__ unsigned short f2bf(float f){
  union { float f; unsigned u; } x; x.f = f;
  return (unsigned short)((x.u + 0x7fffu + ((x.u >> 16) & 1u)) >> 16);
}
__device__ __forceinline__ float bf2f(short s){
  union { unsigned u; float f; } x; x.u = ((unsigned)(unsigned short)s) << 16;
  return x.f;
}
__device__ __forceinline__ float gelu_f(float x){
  return 0.5f*x*(1.f+erff(x*0.70710678118654752f));
}

// ---------------- LayerNorm -> bf16 out ------------------------------------
__global__ __launch_bounds__(256) void ln_bf16(const float* __restrict__ in,
    const float* __restrict__ gg, const float* __restrict__ bb, short* __restrict__ out)
{
  const int row = blockIdx.x;
  const int tid = threadIdx.x;
  const float4 v = reinterpret_cast<const float4*>(in + (size_t)row*1024)[tid];
  float s  = v.x+v.y+v.z+v.w;
  float sq = v.x*v.x+v.y*v.y+v.z*v.z+v.w*v.w;
  #pragma unroll
  for (int off=32; off; off>>=1){ s += __shfl_xor(s,off); sq += __shfl_xor(sq,off); }
  __shared__ float ss[4], qs[4];
  const int wid = tid>>6, lane = tid&63;
  if (lane==0){ ss[wid]=s; qs[wid]=sq; }
  __syncthreads();
  s  = ss[0]+ss[1]+ss[2]+ss[3];
  sq = qs[0]+qs[1]+qs[2]+qs[3];
  const float mu  = s * (1.f/1024.f);
  const float var = sq*(1.f/1024.f) - mu*mu;
  const float rs  = rsqrtf(var + 1e-5f);
  const float4 g4 = reinterpret_cast<const float4*>(gg)[tid];
  const float4 b4 = reinterpret_cast<const float4*>(bb)[tid];
  ushort4 o;
  o.x = f2bf((v.x-mu)*rs*g4.x+b4.x);
  o.y = f2bf((v.y-mu)*rs*g4.y+b4.y);
  o.z = f2bf((v.z-mu)*rs*g4.z+b4.z);
  o.w = f2bf((v.w-mu)*rs*g4.w+b4.w);
  *reinterpret_cast<ushort4*>(out + (size_t)row*1024 + tid*4) = o;
}

// ------------- fused weight prep: all transposes in 1 launch ----------------
__device__ __forceinline__ void conv_body(const float* __restrict__ in,
    short* __restrict__ out, int K, int N, const float* __restrict__ add, int addN,
    int bx, int by)
{
  __shared__ float tile[32][33];
  const int n0 = bx*32, k0 = by*32;
  const int r = threadIdx.x >> 3, c4 = (threadIdx.x & 7)*4;
  float4 v = *reinterpret_cast<const float4*>(&in[(size_t)(k0+r)*N + n0 + c4]);
  if (add && (n0 + c4) < addN) {
    const float* ap = &add[(size_t)(k0+r)*addN + n0 + c4];
    v.x += ap[0]; v.y += ap[1]; v.z += ap[2]; v.w += ap[3];
  }
  tile[r][c4+0]=v.x; tile[r][c4+1]=v.y; tile[r][c4+2]=v.z; tile[r][c4+3]=v.w;
  __syncthreads();
  ushort4 o;
  o.x = f2bf(tile[c4+0][r]); o.y = f2bf(tile[c4+1][r]);
  o.z = f2bf(tile[c4+2][r]); o.w = f2bf(tile[c4+3][r]);
  *reinterpret_cast<ushort4*>(&out[(size_t)(n0+r)*K + k0 + c4]) = o;
}

__global__ __launch_bounds__(256) void prep_weights(
    const float* __restrict__ W_qkv, const float* __restrict__ W_O,
    const float* __restrict__ W_ug,  const float* __restrict__ B_w,
    const float* __restrict__ C_w,   const float* __restrict__ W1,
    const float* __restrict__ W2,
    short* __restrict__ wT_qkv, short* __restrict__ wT_o,
    short* __restrict__ wT_ug,  short* __restrict__ wT_c,
    short* __restrict__ wT_1,   short* __restrict__ wT_2)
{
  const int bid = blockIdx.x;
  if (bid < 3072) {
    conv_body(W_qkv, wT_qkv, 1024, 3072, nullptr, 0, bid % 96, bid / 96);
  } else if (bid < 4224) {
    const int j = bid - 3072;
    conv_body(W_ug, wT_ug, 1024, 1152, B_w, 128, j % 36, j / 36);
  } else if (bid < 5248) {
    const int j = bid - 4224;
    conv_body(W_O, wT_o, 1024, 1024, nullptr, 0, j % 32, j / 32);
  } else if (bid < 5376) {
    const int j = bid - 5248;
    conv_body(C_w, wT_c, 128, 1024, nullptr, 0, j % 32, j / 32);
  } else if (bid < 9472) {
    const int j = bid - 5376;
    conv_body(W1, wT_1, 1024, 4096, nullptr, 0, j % 128, j / 128);
  } else {
    const int j = bid - 9472;
    conv_body(W2, wT_2, 4096, 1024, nullptr, 0, j % 32, j / 32);
  }
}

// ============ 256x256 tile, BK=64, 8 waves, counted-vmcnt pipeline ==========
// EPI: 0 = plain -> bf16 out, 1 = bias+gelu -> bf16 out.
template<int EPI>
__global__ __launch_bounds__(512) void gemm256(
    const short* __restrict__ A, const short* __restrict__ Bt,
    const float* __restrict__ bias, short* __restrict__ Cout,
    int M, int N, int K)
{
  extern __shared__ char lds[];     // 2 bufs x (A 32KB + B 32KB) = 128KB
  const int tid = threadIdx.x;
  const int ln = tid & 63, w = tid >> 6;
  const int wr = w >> 2, wc = w & 3;          // 2 x 4 wave grid
  const int lane15 = ln & 15, lgrp = ln >> 4;

  const int gx = gridDim.x;
  const int nwg = gx * gridDim.y;
  int id = blockIdx.y * gx + blockIdx.x;
  if ((nwg & 7) == 0) { const int cpx = nwg >> 3; id = (id & 7) * cpx + (id >> 3); }
  const int m0 = (id / gx) * 256, n0 = (id % gx) * 256;

  const int NT = K >> 6;

  f32x4 acc[8][4];
  #pragma unroll
  for (int i=0;i<8;i++)
    #pragma unroll
    for (int j=0;j<4;j++) acc[i][j] = (f32x4){0.f,0.f,0.f,0.f};

  #define STG256(k0_, bufA_, bufB_, p_) { \
    const int slot = (p_)*512 + tid; \
    const int row = slot >> 3, blk = slot & 7; \
    const int sblk = blk ^ (row & 7); \
    async16(A  + (size_t)(m0+row)*K + (k0_) + sblk*8, (bufA_) + slot*16); \
    async16(Bt + (size_t)(n0+row)*K + (k0_) + sblk*8, (bufB_) + slot*16); }

  {
    char* bA = lds, *bB = lds + 32768;
    STG256(0, bA, bB, 0); STG256(0, bA, bB, 1); STG256(0, bA, bB, 2); STG256(0, bA, bB, 3);
    if (NT > 1) { char* cA = lds + 65536, *cB = cA + 32768; STG256(64, cA, cB, 0); }
    asm volatile("s_waitcnt vmcnt(0)" ::: "memory");
    __builtin_amdgcn_s_barrier();
    __builtin_amdgcn_sched_barrier(0);
  }

  for (int kt = 0; kt < NT; ++kt) {
    const int cur = kt & 1;
    char* rdA = lds + cur*65536;  char* rdB = rdA + 32768;
    char* wrA = lds + (cur^1)*65536; char* wrB = wrA + 32768;
    const int kn = (kt+1) << 6;
    // ---- B fragments once per tile (8 ds_read_b128) ----
    bf16x8 bfr[4][2];
    #pragma unroll
    for (int ni = 0; ni < 4; ni++) {
      const int row = wc*64 + ni*16 + lane15;
      #pragma unroll
      for (int ks = 0; ks < 2; ks++) {
        const int b = (ks*4 + lgrp) ^ (row & 7);
        bfr[ni][ks] = *reinterpret_cast<const bf16x8*>(rdB + (row*8 + b)*16);
      }
    }
    if (kt+1 < NT) STG256(kn, wrA, wrB, 1);
    // ---- two m-halves: A fragments once each (8 reads), 32 MFMA ----
    #pragma unroll
    for (int mq = 0; mq < 2; ++mq) {
      bf16x8 af[4][2];
      #pragma unroll
      for (int mi = 0; mi < 4; mi++) {
        const int row = wr*128 + (mq*4+mi)*16 + lane15;
        #pragma unroll
        for (int ks = 0; ks < 2; ks++) {
          const int b = (ks*4 + lgrp) ^ (row & 7);
          af[mi][ks] = *reinterpret_cast<const bf16x8*>(rdA + (row*8 + b)*16);
        }
      }
      if (kt+1 < NT) STG256(kn, wrA, wrB, 2+mq);
      #pragma unroll
      for (int mi = 0; mi < 4; mi++)
        #pragma unroll
        for (int ni = 0; ni < 4; ni++)
          #pragma unroll
          for (int ks = 0; ks < 2; ks++)
            acc[mq*4+mi][ni] = __builtin_amdgcn_mfma_f32_16x16x32_bf16(
                af[mi][ks], bfr[ni][ks], acc[mq*4+mi][ni], 0, 0, 0);
    }
    if (kt+1 < NT) {
      __builtin_amdgcn_s_barrier();
      if (kt+2 < NT) {
        STG256((kt+2) << 6, rdA, rdB, 0);
        asm volatile("s_waitcnt vmcnt(2)" ::: "memory");
      } else {
        asm volatile("s_waitcnt vmcnt(0)" ::: "memory");
      }
      __builtin_amdgcn_s_barrier();
      __builtin_amdgcn_sched_barrier(0);
    }
  }
  #undef STG256

  #pragma unroll
  for (int ni = 0; ni < 4; ni++) {
    const int col = n0 + wc*64 + ni*16 + lane15;
    const float bv = bias ? bias[col] : 0.f;
    #pragma unroll
    for (int mi = 0; mi < 8; mi++) {
      #pragma unroll
      for (int r = 0; r < 4; r++) {
        const int row = m0 + wr*128 + mi*16 + lgrp*4 + r;
        float v = acc[mi][ni][r] + bv;
        if (EPI == 1) v = gelu_f(v);
        Cout[(size_t)row*N + col] = (short)f2bf(v);
      }
    }
  }
}

// ====== BM x 128 tile (BM = MT*32), BK=64, 4 waves, counted-vmcnt pipeline ==
// EPI: 1 = UG split: col<128 -> drive fp32[.][128]; col>=128 -> sigmoid bf16 gate
//      3 = RES: out = acc + bias + out  (fp32, in-place resid)
template<int MT, int EPI>
__global__ __launch_bounds__(256) void gemm128(
    const short* __restrict__ A, const short* __restrict__ Bt,
    const float* __restrict__ bias,
    short* __restrict__ e_g,
    void* __restrict__ Cout, int M, int N, int K)
{
  constexpr int BM  = MT * 32;
  constexpr int ABY = BM * 128;
  constexpr int STR = ABY + 16384;
  constexpr int MPQ = MT / 2;
  extern __shared__ char lds[];
  const int tid = threadIdx.x;
  const int ln = tid & 63, w = tid >> 6;
  const int wr = w >> 1, wc = w & 1;
  const int lane15 = ln & 15, lgrp = ln >> 4;

  const int gx = gridDim.x;
  const int nwg = gx * gridDim.y;
  int id = blockIdx.y * gx + blockIdx.x;
  if ((nwg & 7) == 0) { const int cpx = nwg >> 3; id = (id & 7) * cpx + (id >> 3); }
  const int m0 = (id / gx) * BM, n0 = (id % gx) * 128;

  const int NT = K >> 6;

  f32x4 acc[MT][4];
  #pragma unroll
  for (int i=0;i<MT;i++)
    #pragma unroll
    for (int j=0;j<4;j++) acc[i][j] = (f32x4){0.f,0.f,0.f,0.f};

  #define STG(k0_, bufA_, bufB_, p_) { \
    const int slot = (p_)*256 + tid; \
    const int row = slot >> 3, blk = slot & 7; \
    const int sblk = blk ^ (row & 7); \
    if ((p_) < MT) async16(A + (size_t)(m0+row)*K + (k0_) + sblk*8, (bufA_) + slot*16); \
    async16(Bt + (size_t)(n0+row)*K + (k0_) + sblk*8, (bufB_) + slot*16); }

  {
    char* bA = lds, *bB = lds + ABY;
    STG(0, bA, bB, 0); STG(0, bA, bB, 1); STG(0, bA, bB, 2); STG(0, bA, bB, 3);
    if (NT > 1) { char* cA = lds + STR, *cB = cA + ABY; STG(64, cA, cB, 0); }
    asm volatile("s_waitcnt vmcnt(0)" ::: "memory");
    __builtin_amdgcn_s_barrier();
    __builtin_amdgcn_sched_barrier(0);
  }

  for (int kt = 0; kt < NT; ++kt) {
    const int cur = kt & 1;
    char* rdA = lds + cur*STR;   char* rdB = rdA + ABY;
    char* wrA = lds + (cur^1)*STR; char* wrB = wrA + ABY;
    const int kn = (kt+1) << 6;
    bf16x8 bfr[4][2];
    #pragma unroll
    for (int ni = 0; ni < 4; ni++) {
      const int row = wc*64 + ni*16 + lane15;
      #pragma unroll
      for (int ks = 0; ks < 2; ks++) {
        const int b = (ks*4 + lgrp) ^ (row & 7);
        bfr[ni][ks] = *reinterpret_cast<const bf16x8*>(rdB + (row*8 + b)*16);
      }
    }
    if (kt+1 < NT) STG(kn, wrA, wrB, 1);
    #pragma unroll
    for (int mq = 0; mq < 2; ++mq) {
      bf16x8 af[MPQ][2];
      #pragma unroll
      for (int mi = 0; mi < MPQ; mi++) {
        const int row = wr*(MT*16) + (mq*MPQ+mi)*16 + lane15;
        #pragma unroll
        for (int ks = 0; ks < 2; ks++) {
          const int b = (ks*4 + lgrp) ^ (row & 7);
          af[mi][ks] = *reinterpret_cast<const bf16x8*>(rdA + (row*8 + b)*16);
        }
      }
      if (kt+1 < NT) STG(kn, wrA, wrB, 2+mq);
      #pragma unroll
      for (int mi = 0; mi < MPQ; mi++)
        #pragma unroll
        for (int ni = 0; ni < 4; ni++)
          #pragma unroll
          for (int ks = 0; ks < 2; ks++)
            acc[mq*MPQ+mi][ni] = __builtin_amdgcn_mfma_f32_16x16x32_bf16(
                af[mi][ks], bfr[ni][ks], acc[mq*MPQ+mi][ni], 0, 0, 0);
    }
    if (kt+1 < NT) {
      __builtin_amdgcn_s_barrier();
      if (kt+2 < NT) {
        STG((kt+2) << 6, rdA, rdB, 0);
        asm volatile("s_waitcnt vmcnt(2)" ::: "memory");
      } else {
        asm volatile("s_waitcnt vmcnt(0)" ::: "memory");
      }
      __builtin_amdgcn_s_barrier();
      __builtin_amdgcn_sched_barrier(0);
    }
  }
  #undef STG

  #pragma unroll
  for (int ni = 0; ni < 4; ni++) {
    const int col = n0 + wc*64 + ni*16 + lane15;
    const float bv = bias ? bias[col] : 0.f;
    #pragma unroll
    for (int mi = 0; mi < MT; mi++) {
      #pragma unroll
      for (int r = 0; r < 4; r++) {
        const int row = m0 + wr*(MT*16) + mi*16 + lgrp*4 + r;
        float v = acc[mi][ni][r] + bv;
        if (EPI == 1) {
          if (col < 128) ((float*)Cout)[(size_t)row*128 + col] = v;
          else {
            const float gs = 1.f/(1.f+__expf(-v));
            e_g[(size_t)row*1024 + col - 128] = (short)f2bf(gs);
          }
        } else {
          float* o = (float*)Cout;
          o[(size_t)row*N + col] = v + o[(size_t)row*N + col];
        }
      }
    }
  }
}

// ====== Fused W_O + C_w combine: out = x + g*(attn@WO+bO) + (1-g)*(st@Cw) ===
__global__ __launch_bounds__(256) void wo_comb(
    const short* __restrict__ A1, const short* __restrict__ B1t,
    const short* __restrict__ A2, const short* __restrict__ B2t,
    const float* __restrict__ bias, const float* __restrict__ e_x,
    const short* __restrict__ e_g, float* __restrict__ Cout)
{
  constexpr int ABY = 8192;
  constexpr int STR = ABY + 16384;
  extern __shared__ char lds[];
  const int tid = threadIdx.x;
  const int ln = tid & 63, w = tid >> 6;
  const int wr = w >> 1, wc = w & 1;
  const int lane15 = ln & 15, lgrp = ln >> 4;
  const int K = 1024, N = 1024;

  const int gx = gridDim.x;
  const int nwg = gx * gridDim.y;
  int id = blockIdx.y * gx + blockIdx.x;
  if ((nwg & 7) == 0) { const int cpx = nwg >> 3; id = (id & 7) * cpx + (id >> 3); }
  const int m0 = (id / gx) * 64, n0 = (id % gx) * 128;

  f32x4 acc1[2][4], acc2[2][4];
  #pragma unroll
  for (int i=0;i<2;i++)
    #pragma unroll
    for (int j=0;j<4;j++){ acc1[i][j] = (f32x4){0.f,0.f,0.f,0.f}; acc2[i][j] = (f32x4){0.f,0.f,0.f,0.f}; }

  #define STGW(Asrc_, Bsrc_, AK_, k0_, bufA_, bufB_, p_) { \
    const int slot = (p_)*256 + tid; \
    const int row = slot >> 3, blk = slot & 7; \
    const int sblk = blk ^ (row & 7); \
    if ((p_) < 2) async16(Asrc_ + (size_t)(m0+row)*(AK_) + (k0_) + sblk*8, (bufA_) + slot*16); \
    async16(Bsrc_ + (size_t)(n0+row)*(AK_) + (k0_) + sblk*8, (bufB_) + slot*16); }

  {
    char* bA = lds, *bB = lds + ABY;
    STGW(A1, B1t, K, 0, bA, bB, 0); STGW(A1, B1t, K, 0, bA, bB, 1);
    STGW(A1, B1t, K, 0, bA, bB, 2); STGW(A1, B1t, K, 0, bA, bB, 3);
    { char* cA = lds + STR, *cB = cA + ABY; STGW(A1, B1t, K, 64, cA, cB, 0); }
    asm volatile("s_waitcnt vmcnt(0)" ::: "memory");
    __builtin_amdgcn_s_barrier();
    __builtin_amdgcn_sched_barrier(0);
  }

  const int NT = 16;
  for (int kt = 0; kt < NT; ++kt) {
    const int cur = kt & 1;
    char* rdA = lds + cur*STR;   char* rdB = rdA + ABY;
    char* wrA = lds + (cur^1)*STR; char* wrB = wrA + ABY;
    const int kn = (kt+1) << 6;
    bf16x8 bfr[4][2];
    #pragma unroll
    for (int ni = 0; ni < 4; ni++) {
      const int row = wc*64 + ni*16 + lane15;
      #pragma unroll
      for (int ks = 0; ks < 2; ks++) {
        const int b = (ks*4 + lgrp) ^ (row & 7);
        bfr[ni][ks] = *reinterpret_cast<const bf16x8*>(rdB + (row*8 + b)*16);
      }
    }
    if (kt+1 < NT) STGW(A1, B1t, K, kn, wrA, wrB, 1);
    #pragma unroll
    for (int mq = 0; mq < 2; ++mq) {
      bf16x8 af[2];
      {
        const int row = wr*32 + mq*16 + lane15;
        #pragma unroll
        for (int ks = 0; ks < 2; ks++) {
          const int b = (ks*4 + lgrp) ^ (row & 7);
          af[ks] = *reinterpret_cast<const bf16x8*>(rdA + (row*8 + b)*16);
        }
      }
      if (kt+1 < NT) STGW(A1, B1t, K, kn, wrA, wrB, 2+mq);
      #pragma unroll
      for (int ni = 0; ni < 4; ni++)
        #pragma unroll
        for (int ks = 0; ks < 2; ks++)
          acc1[mq][ni] = __builtin_amdgcn_mfma_f32_16x16x32_bf16(
              af[ks], bfr[ni][ks], acc1[mq][ni], 0, 0, 0);
    }
    if (kt+1 < NT) {
      __builtin_amdgcn_s_barrier();
      if (kt+2 < NT) {
        STGW(A1, B1t, K, (kt+2) << 6, rdA, rdB, 0);
        asm volatile("s_waitcnt vmcnt(2)" ::: "memory");
      } else {
        asm volatile("s_waitcnt vmcnt(0)" ::: "memory");
      }
      __builtin_amdgcn_s_barrier();
      __builtin_amdgcn_sched_barrier(0);
    }
  }

  __builtin_amdgcn_s_barrier();
  {
    char* bA0 = lds,       *bB0 = lds + ABY;
    char* bA1 = lds + STR, *bB1 = bA1 + ABY;
    STGW(A2, B2t, 128, 0,  bA0, bB0, 0); STGW(A2, B2t, 128, 0,  bA0, bB0, 1);
    STGW(A2, B2t, 128, 0,  bA0, bB0, 2); STGW(A2, B2t, 128, 0,  bA0, bB0, 3);
    STGW(A2, B2t, 128, 64, bA1, bB1, 0); STGW(A2, B2t, 128, 64, bA1, bB1, 1);
    STGW(A2, B2t, 128, 64, bA1, bB1, 2); STGW(A2, B2t, 128, 64, bA1, bB1, 3);
    asm volatile("s_waitcnt vmcnt(0)" ::: "memory");
    __builtin_amdgcn_s_barrier();
  }
  #pragma unroll
  for (int t2 = 0; t2 < 2; ++t2) {
    char* rdA = lds + t2*STR; char* rdB = rdA + ABY;
    bf16x8 bfr2[4][2];
    #pragma unroll
    for (int ni = 0; ni < 4; ni++) {
      const int brow = wc*64 + ni*16 + lane15;
      #pragma unroll
      for (int ks = 0; ks < 2; ks++) {
        const int b = (ks*4 + lgrp) ^ (brow & 7);
        bfr2[ni][ks] = *reinterpret_cast<const bf16x8*>(rdB + (brow*8 + b)*16);
      }
    }
    #pragma unroll
    for (int mi = 0; mi < 2; mi++) {
      bf16x8 af[2];
      const int row = wr*32 + mi*16 + lane15;
      #pragma unroll
      for (int ks = 0; ks < 2; ks++) {
        const int b = (ks*4 + lgrp) ^ (row & 7);
        af[ks] = *reinterpret_cast<const bf16x8*>(rdA + (row*8 + b)*16);
      }
      #pragma unroll
      for (int ni = 0; ni < 4; ni++)
        #pragma unroll
        for (int ks = 0; ks < 2; ks++)
          acc2[mi][ni] = __builtin_amdgcn_mfma_f32_16x16x32_bf16(af[ks], bfr2[ni][ks], acc2[mi][ni], 0, 0, 0);
    }
  }
  #undef STGW

  #pragma unroll
  for (int ni = 0; ni < 4; ni++) {
    const int col = n0 + wc*64 + ni*16 + lane15;
    const float bv = bias[col];
    #pragma unroll
    for (int mi = 0; mi < 2; mi++) {
      #pragma unroll
      for (int r = 0; r < 4; r++) {
        const int row = m0 + wr*32 + mi*16 + lgrp*4 + r;
        const float g = bf2f(e_g[(size_t)row*1024 + col]);
        Cout[(size_t)row*N + col] = e_x[(size_t)row*1024 + col]
            + g*(acc1[mi][ni][r] + bv) + (1.f-g)*acc2[mi][ni][r];
      }
    }
  }
}

// ---------------- Flash sliding-window attention (MFMA, bf16) ---------------
#define ATS 72
__global__ __launch_bounds__(256) void attn_mfma(const short* __restrict__ qkv,
                                                 short* __restrict__ attn_out)
{
  __shared__ short Qs[64*ATS];
  __shared__ short Ks[64*ATS];
  __shared__ short Vt[64*ATS];
  __shared__ short Ps[4][16*ATS];
  const int tid = threadIdx.x;
  const int ln = tid & 63, w = tid >> 6;
  const int qt0 = (blockIdx.x >> 4) * 64;
  const int h = blockIdx.x & 15;

  {
    const int jr = tid >> 3, d0 = (tid & 7) * 8;
    #pragma unroll
    for (int p = 0; p < 2; p++) {
      const int j = jr + p*32;
      const bf16x8 v = *reinterpret_cast<const bf16x8*>(&qkv[(size_t)(qt0 + j)*3072 + h*64 + d0]);
      const int blk = (d0 >> 3) ^ (j & 7);
      *reinterpret_cast<bf16x8*>(&Qs[j*ATS + blk*8]) = v;
    }
  }

  float mrow[4], lrow[4];
  f32x4 oacc[4];
  #pragma unroll
  for (int r=0;r<4;r++){ mrow[r] = -1e30f; lrow[r] = 0.f; }
  #pragma unroll
  for (int df=0;df<4;df++) oacc[df] = (f32x4){0.f,0.f,0.f,0.f};

  const int qrow_lane = w*16 + (ln>>4)*4;
  const int qtile = qt0 >> 6;
  const int cstart = (qtile >= 4) ? 0 : (4 - qtile);

  for (int c = cstart; c < 5; c++) {
    const int cs = qt0 - 256 + c*64;
    {
      const int jr = tid >> 3, d0 = (tid & 7) * 8;
      #pragma unroll
      for (int p = 0; p < 2; p++) {
        const int j = jr + p*32;
        const size_t krow = (size_t)(cs + j)*3072 + h*64;
        const bf16x8 kv = *reinterpret_cast<const bf16x8*>(&qkv[krow + 1024 + d0]);
        const int blk = (d0>>3) ^ (j & 7);
        *reinterpret_cast<bf16x8*>(&Ks[j*ATS + blk*8]) = kv;
        const bf16x8 vv = *reinterpret_cast<const bf16x8*>(&qkv[krow + 2048 + d0]);
        #pragma unroll
        for (int i = 0; i < 8; i++) {
          const int d = d0 + i;
          const int jb = (j >> 3) ^ ((d >> 3) & 7);
          Vt[d*ATS + jb*8 + (j & 7)] = ((const short*)&vv)[i];
        }
      }
    }
    __syncthreads();

    bf16x8 aq[2];
    #pragma unroll
    for (int ks=0; ks<2; ks++){
      const int row = w*16 + (ln & 15);
      const int b = (ks*4 + (ln>>4)) ^ (row & 7);
      aq[ks] = *reinterpret_cast<const bf16x8*>(&Qs[row*ATS + b*8]);
    }
    float sv[4][4];
    #pragma unroll
    for (int nf=0; nf<4; nf++){
      const int krow = nf*16 + (ln & 15);
      f32x4 s = (f32x4){0.f,0.f,0.f,0.f};
      #pragma unroll
      for (int ks=0; ks<2; ks++){
        const int b = (ks*4 + (ln>>4)) ^ (krow & 7);
        const bf16x8 bk = *reinterpret_cast<const bf16x8*>(&Ks[krow*ATS + b*8]);
        s = __builtin_amdgcn_mfma_f32_16x16x32_bf16(aq[ks], bk, s, 0, 0, 0);
      }
      const int k_abs = cs + nf*16 + (ln & 15);
      #pragma unroll
      for (int r=0;r<4;r++){
        const int t_abs = qt0 + qrow_lane + r;
        const bool valid = (k_abs <= t_abs) && (k_abs >= t_abs - 255);
        sv[nf][r] = valid ? s[r]*0.125f : -1e30f;
      }
    }
    float cm[4], alpha[4], rs[4];
    #pragma unroll
    for (int r=0;r<4;r++){
      cm[r] = fmaxf(fmaxf(sv[0][r],sv[1][r]), fmaxf(sv[2][r],sv[3][r]));
      #pragma unroll
      for (int off=1; off<16; off<<=1) cm[r] = fmaxf(cm[r], __shfl_xor(cm[r], off));
      const float mnew = fmaxf(mrow[r], cm[r]);
      alpha[r] = __expf(mrow[r] - mnew);
      mrow[r] = mnew;
      rs[r] = 0.f;
    }
    #pragma unroll
    for (int nf=0; nf<4; nf++){
      const int pcol = nf*16 + (ln & 15);
      #pragma unroll
      for (int r=0;r<4;r++){
        const float p = (sv[nf][r] <= -1e29f) ? 0.f : __expf(sv[nf][r] - mrow[r]);
        rs[r] += p;
        const int prow = (ln>>4)*4 + r;
        const int pb = (pcol>>3) ^ (prow & 7);
        Ps[w][prow*ATS + pb*8 + (pcol & 7)] = (short)f2bf(p);
      }
    }
    #pragma unroll
    for (int r=0;r<4;r++){
      #pragma unroll
      for (int off=1; off<16; off<<=1) rs[r] += __shfl_xor(rs[r], off);
      lrow[r] = lrow[r]*alpha[r] + rs[r];
      #pragma unroll
      for (int df=0; df<4; df++) oacc[df][r] *= alpha[r];
    }
    bf16x8 ap[2];
    #pragma unroll
    for (int ks=0; ks<2; ks++){
      const int prow = (ln & 15);
      const int b = (ks*4 + (ln>>4)) ^ (prow & 7);
      ap[ks] = *reinterpret_cast<const bf16x8*>(&Ps[w][prow*ATS + b*8]);
    }
    #pragma unroll
    for (int df=0; df<4; df++){
      const int vrow = df*16 + (ln & 15);
      #pragma unroll
      for (int ks=0; ks<2; ks++){
        const int b = (ks*4 + (ln>>4)) ^ ((vrow>>3) & 7);
        const bf16x8 bv = *reinterpret_cast<const bf16x8*>(&Vt[vrow*ATS + b*8]);
        oacc[df] = __builtin_amdgcn_mfma_f32_16x16x32_bf16(ap[ks], bv, oacc[df], 0, 0, 0);
      }
    }
    __syncthreads();
  }

  #pragma unroll
  for (int df=0; df<4; df++)
    #pragma unroll
    for (int r=0; r<4; r++){
      const int t = qt0 + qrow_lane + r;
      const int d = df*16 + (ln & 15);
      attn_out[(size_t)t*1024 + h*64 + d] = (short)f2bf(oacc[df][r] / lrow[r]);
    }
}

// ---------------- SSM scan as 16-tap convolution (compact drive) ------------
__global__ __launch_bounds__(256) void scan_kernel(const float* __restrict__ drive,
    const float* __restrict__ Aa, short* __restrict__ states)
{
  const int idx = blockIdx.x*256 + threadIdx.x;
  const int t = idx >> 7, s = idx & 127;
  const float a = Aa[s];
  float acc = 0.f, pw = 1.f;
  const int kmax = (t+1 < 16) ? (t+1) : 16;
  for (int k=0;k<kmax;k++){
    acc = fmaf(pw, drive[(size_t)(t-k)*128 + s], acc);
    pw *= a;
  }
  states[idx] = (short)f2bf(acc);
}

extern "C" void kernel_launch(void* const* d_in, const int* in_sizes, int n_in,
                              void* d_out, int out_size, void* d_ws, size_t ws_size,
                              hipStream_t stream)
{
  const float* x     = (const float*)d_in[0];
  const float* ln1_g = (const float*)d_in[1];
  const float* ln1_b = (const float*)d_in[2];
  const float* ln2_g = (const float*)d_in[3];
  const float* ln2_b = (const float*)d_in[4];
  const float* W_qkv = (const float*)d_in[5];
  const float* W_O   = (const float*)d_in[6];
  const float* b_O   = (const float*)d_in[7];
  const float* W_ug  = (const float*)d_in[8];
  const float* b_ug  = (const float*)d_in[9];
  const float* B_w   = (const float*)d_in[10];
  const float* A     = (const float*)d_in[11];
  const float* C_w   = (const float*)d_in[12];
  const float* W1    = (const float*)d_in[13];
  const float* b1    = (const float*)d_in[14];
  const float* W2    = (const float*)d_in[15];
  const float* b2    = (const float*)d_in[16];
  float* out = (float*)d_out;
  char* ws = (char*)d_ws;

  short* qkv_bf = (short*)(ws + 0);          // 24MB
  short* attn_bf= (short*)(ws + 25165824);   // 8MB
  short* xn_bf  = (short*)(ws + 33554432);   // 8MB (h aliases)
  short* g_bf   = (short*)(ws + 41943040);   // 8MB
  float* drive  = (float*)(ws + 50331648);   // 2MB
  short* st_bf  = (short*)(ws + 52428800);   // 1MB
  short* wT_qkv = (short*)(ws + 53542912);   // 6MB
  short* wT_o   = (short*)(ws + 59834368);   // 2MB
  short* wT_ug  = (short*)(ws + 61931520);   // 2.25MB
  short* wT_c   = (short*)(ws + 64290816);   // 0.25MB
  short* wT_1   = (short*)(ws + 64552960);   // 8MB
  short* wT_2   = (short*)(ws + 72941568);   // 8MB
  short* mid_bf = (short*)(ws + 0);          // 32MB alias (dead qkv+attn)
  short* h_bf   = xn_bf;

  static bool attr_done = false;
  if (!attr_done) {
    hipFuncSetAttribute((const void*)gemm256<0>, hipFuncAttributeMaxDynamicSharedMemorySize, 131072);
    hipFuncSetAttribute((const void*)gemm256<1>, hipFuncAttributeMaxDynamicSharedMemorySize, 131072);
    hipFuncSetAttribute((const void*)(gemm128<2,1>), hipFuncAttributeMaxDynamicSharedMemorySize, 49152);
    hipFuncSetAttribute((const void*)(gemm128<2,3>), hipFuncAttributeMaxDynamicSharedMemorySize, 49152);
    hipFuncSetAttribute((const void*)wo_comb, hipFuncAttributeMaxDynamicSharedMemorySize, 49152);
    attr_done = true;
  }

  prep_weights<<<13568, 256, 0, stream>>>(W_qkv, W_O, W_ug, B_w, C_w, W1, W2,
                                          wT_qkv, wT_o, wT_ug, wT_c, wT_1, wT_2);

  ln_bf16<<<4096, 256, 0, stream>>>(x, ln1_g, ln1_b, xn_bf);
  gemm256<0><<<dim3(12,16), 512, 131072, stream>>>(xn_bf, wT_qkv, nullptr, qkv_bf, 4096, 3072, 1024);
  attn_mfma<<<1024, 256, 0, stream>>>(qkv_bf, attn_bf);
  gemm128<2,1><<<dim3(9,64), 256, 49152, stream>>>(xn_bf, wT_ug, b_ug, g_bf, drive, 4096, 1152, 1024);
  scan_kernel<<<2048, 256, 0, stream>>>(drive, A, st_bf);
  wo_comb<<<dim3(8,64), 256, 49152, stream>>>(attn_bf, wT_o, st_bf, wT_c, b_O, x, g_bf, out);
  ln_bf16<<<4096, 256, 0, stream>>>(out, ln2_g, ln2_b, h_bf);
  gemm256<1><<<dim3(16,16), 512, 131072, stream>>>(h_bf, wT_1, b1, mid_bf, 4096, 4096, 1024);
  gemm128<2,3><<<dim3(8,64), 256, 49152, stream>>>(mid_bf, wT_2, b2, nullptr, out, 4096, 1024, 4096);
}

// Round 17
// 239.791 us; speedup vs baseline: 1.0567x; 1.0120x over previous
//
#include <hip/hip_runtime.h>
#include <hip/hip_bf16.h>
#include <math.h>

typedef short bf16x8 __attribute__((ext_vector_type(8)));
typedef float f32x4  __attribute__((ext_vector_type(4)));

#define GLOBAL_AS __attribute__((address_space(1)))
#define LDS_AS    __attribute__((address_space(3)))

__device__ __forceinline__ void async16(const void* g, void* l) {
  __builtin_amdgcn_global_load_lds((GLOBAL_AS void*)(g), (LDS_AS void*)(l), 16, 0, 0);
}

__device__ __forceinline__ unsigned short f2bf(float f){
  union { float f; unsigned u; } x; x.f = f;
  return (unsigned short)((x.u + 0x7fffu + ((x.u >> 16) & 1u)) >> 16);
}
__device__ __forceinline__ float bf2f(short s){
  union { unsigned u; float f; } x; x.u = ((unsigned)(unsigned short)s) << 16;
  return x.f;
}
__device__ __forceinline__ float gelu_f(float x){
  return 0.5f*x*(1.f+erff(x*0.70710678118654752f));
}

// ---------------- LayerNorm -> bf16 out ------------------------------------
__global__ __launch_bounds__(256) void ln_bf16(const float* __restrict__ in,
    const float* __restrict__ gg, const float* __restrict__ bb, short* __restrict__ out)
{
  const int row = blockIdx.x;
  const int tid = threadIdx.x;
  const float4 v = reinterpret_cast<const float4*>(in + (size_t)row*1024)[tid];
  float s  = v.x+v.y+v.z+v.w;
  float sq = v.x*v.x+v.y*v.y+v.z*v.z+v.w*v.w;
  #pragma unroll
  for (int off=32; off; off>>=1){ s += __shfl_xor(s,off); sq += __shfl_xor(sq,off); }
  __shared__ float ss[4], qs[4];
  const int wid = tid>>6, lane = tid&63;
  if (lane==0){ ss[wid]=s; qs[wid]=sq; }
  __syncthreads();
  s  = ss[0]+ss[1]+ss[2]+ss[3];
  sq = qs[0]+qs[1]+qs[2]+qs[3];
  const float mu  = s * (1.f/1024.f);
  const float var = sq*(1.f/1024.f) - mu*mu;
  const float rs  = rsqrtf(var + 1e-5f);
  const float4 g4 = reinterpret_cast<const float4*>(gg)[tid];
  const float4 b4 = reinterpret_cast<const float4*>(bb)[tid];
  ushort4 o;
  o.x = f2bf((v.x-mu)*rs*g4.x+b4.x);
  o.y = f2bf((v.y-mu)*rs*g4.y+b4.y);
  o.z = f2bf((v.z-mu)*rs*g4.z+b4.z);
  o.w = f2bf((v.w-mu)*rs*g4.w+b4.w);
  *reinterpret_cast<ushort4*>(out + (size_t)row*1024 + tid*4) = o;
}

// ------------- fused weight prep: all transposes in 1 launch ----------------
__device__ __forceinline__ void conv_body(const float* __restrict__ in,
    short* __restrict__ out, int K, int N, const float* __restrict__ add, int addN,
    int bx, int by)
{
  __shared__ float tile[32][33];
  const int n0 = bx*32, k0 = by*32;
  const int r = threadIdx.x >> 3, c4 = (threadIdx.x & 7)*4;
  float4 v = *reinterpret_cast<const float4*>(&in[(size_t)(k0+r)*N + n0 + c4]);
  if (add && (n0 + c4) < addN) {
    const float* ap = &add[(size_t)(k0+r)*addN + n0 + c4];
    v.x += ap[0]; v.y += ap[1]; v.z += ap[2]; v.w += ap[3];
  }
  tile[r][c4+0]=v.x; tile[r][c4+1]=v.y; tile[r][c4+2]=v.z; tile[r][c4+3]=v.w;
  __syncthreads();
  ushort4 o;
  o.x = f2bf(tile[c4+0][r]); o.y = f2bf(tile[c4+1][r]);
  o.z = f2bf(tile[c4+2][r]); o.w = f2bf(tile[c4+3][r]);
  *reinterpret_cast<ushort4*>(&out[(size_t)(n0+r)*K + k0 + c4]) = o;
}

__global__ __launch_bounds__(256) void prep_weights(
    const float* __restrict__ W_qkv, const float* __restrict__ W_O,
    const float* __restrict__ W_ug,  const float* __restrict__ B_w,
    const float* __restrict__ C_w,   const float* __restrict__ W1,
    const float* __restrict__ W2,
    short* __restrict__ wT_qkv, short* __restrict__ wT_o,
    short* __restrict__ wT_ug,  short* __restrict__ wT_c,
    short* __restrict__ wT_1,   short* __restrict__ wT_2)
{
  const int bid = blockIdx.x;
  if (bid < 3072) {
    conv_body(W_qkv, wT_qkv, 1024, 3072, nullptr, 0, bid % 96, bid / 96);
  } else if (bid < 4224) {
    const int j = bid - 3072;
    conv_body(W_ug, wT_ug, 1024, 1152, B_w, 128, j % 36, j / 36);
  } else if (bid < 5248) {
    const int j = bid - 4224;
    conv_body(W_O, wT_o, 1024, 1024, nullptr, 0, j % 32, j / 32);
  } else if (bid < 5376) {
    const int j = bid - 5248;
    conv_body(C_w, wT_c, 128, 1024, nullptr, 0, j % 32, j / 32);
  } else if (bid < 9472) {
    const int j = bid - 5376;
    conv_body(W1, wT_1, 1024, 4096, nullptr, 0, j % 128, j / 128);
  } else {
    const int j = bid - 9472;
    conv_body(W2, wT_2, 4096, 1024, nullptr, 0, j % 32, j / 32);
  }
}

// ======== 256 x BN tile, BK=64, 8 waves (2x4), counted-vmcnt pipeline =======
// BN in {192, 256}. Per wave: 128 x (BN/4), NI = BN/64 n-fragments.
// EPI: 0 = plain -> bf16 out, 1 = bias+gelu -> bf16 out.
template<int BN, int EPI>
__global__ __launch_bounds__(512) void gemm256(
    const short* __restrict__ A, const short* __restrict__ Bt,
    const float* __restrict__ bias, short* __restrict__ Cout,
    int M, int N, int K)
{
  constexpr int NI  = BN / 64;          // n-fragments per wave
  constexpr int NB  = BN / 64;          // B staging calls (64 rows each)
  constexpr int BBY = BN * 128;         // B buffer bytes
  constexpr int STR = 32768 + BBY;      // one dbuf half (A 32KB + B)
  extern __shared__ char lds[];         // 2 * STR
  const int tid = threadIdx.x;
  const int ln = tid & 63, w = tid >> 6;
  const int wr = w >> 2, wc = w & 3;    // 2 x 4 wave grid
  const int lane15 = ln & 15, lgrp = ln >> 4;

  const int gx = gridDim.x;
  const int nwg = gx * gridDim.y;
  int id = blockIdx.y * gx + blockIdx.x;
  if ((nwg & 7) == 0) { const int cpx = nwg >> 3; id = (id & 7) * cpx + (id >> 3); }
  const int m0 = (id / gx) * 256, n0 = (id % gx) * BN;

  const int NT = K >> 6;

  f32x4 acc[8][NI];
  #pragma unroll
  for (int i=0;i<8;i++)
    #pragma unroll
    for (int j=0;j<NI;j++) acc[i][j] = (f32x4){0.f,0.f,0.f,0.f};

  // A staging: 4 calls x 512 slots (1 load/thread); rows 0..255
  #define STGA(k0_, buf_, p_) { \
    const int slot = (p_)*512 + tid; \
    const int row = slot >> 3, blk = slot & 7; \
    const int sblk = blk ^ (row & 7); \
    async16(A + (size_t)(m0+row)*K + (k0_) + sblk*8, (buf_) + slot*16); }

  // B staging: NB calls x 512 slots; rows 0..BN-1
  #define STGB(k0_, buf_, p_) { \
    const int slot = (p_)*512 + tid; \
    const int row = slot >> 3, blk = slot & 7; \
    const int sblk = blk ^ (row & 7); \
    async16(Bt + (size_t)(n0+row)*K + (k0_) + sblk*8, (buf_) + 32768 + slot*16); }

  {
    char* b0 = lds;
    STGA(0, b0, 0); STGA(0, b0, 1); STGA(0, b0, 2); STGA(0, b0, 3);
    #pragma unroll
    for (int p = 0; p < NB; p++) STGB(0, b0, p);
    if (NT > 1) { char* b1 = lds + STR; STGA(64, b1, 0); STGB(64, b1, 0); }
    asm volatile("s_waitcnt vmcnt(0)" ::: "memory");
    __builtin_amdgcn_s_barrier();
    __builtin_amdgcn_sched_barrier(0);
  }

  for (int kt = 0; kt < NT; ++kt) {
    const int cur = kt & 1;
    char* rdbuf = lds + cur*STR;
    char* rdA = rdbuf; char* rdB = rdbuf + 32768;
    char* wrbuf = lds + (cur^1)*STR;
    const int kn = (kt+1) << 6;
    // ---- B fragments once per tile ----
    bf16x8 bfr[NI][2];
    #pragma unroll
    for (int ni = 0; ni < NI; ni++) {
      const int row = wc*(BN/4) + ni*16 + lane15;
      #pragma unroll
      for (int ks = 0; ks < 2; ks++) {
        const int b = (ks*4 + lgrp) ^ (row & 7);
        bfr[ni][ks] = *reinterpret_cast<const bf16x8*>(rdB + (row*8 + b)*16);
      }
    }
    if (kt+1 < NT) {
      STGA(kn, wrbuf, 3);
      #pragma unroll
      for (int p = 1; p < NB; p++) STGB(kn, wrbuf, p);
    }
    // ---- two m-halves ----
    #pragma unroll
    for (int mq = 0; mq < 2; ++mq) {
      bf16x8 af[4][2];
      #pragma unroll
      for (int mi = 0; mi < 4; mi++) {
        const int row = wr*128 + (mq*4+mi)*16 + lane15;
        #pragma unroll
        for (int ks = 0; ks < 2; ks++) {
          const int b = (ks*4 + lgrp) ^ (row & 7);
          af[mi][ks] = *reinterpret_cast<const bf16x8*>(rdA + (row*8 + b)*16);
        }
      }
      if (kt+1 < NT) STGA(kn, wrbuf, 1+mq);
      #pragma unroll
      for (int mi = 0; mi < 4; mi++)
        #pragma unroll
        for (int ni = 0; ni < NI; ni++)
          #pragma unroll
          for (int ks = 0; ks < 2; ks++)
            acc[mq*4+mi][ni] = __builtin_amdgcn_mfma_f32_16x16x32_bf16(
                af[mi][ks], bfr[ni][ks], acc[mq*4+mi][ni], 0, 0, 0);
    }
    if (kt+1 < NT) {
      __builtin_amdgcn_s_barrier();
      if (kt+2 < NT) {
        STGA((kt+2) << 6, rdbuf, 0);
        STGB((kt+2) << 6, rdbuf, 0);
        asm volatile("s_waitcnt vmcnt(2)" ::: "memory");
      } else {
        asm volatile("s_waitcnt vmcnt(0)" ::: "memory");
      }
      __builtin_amdgcn_s_barrier();
      __builtin_amdgcn_sched_barrier(0);
    }
  }
  #undef STGA
  #undef STGB

  #pragma unroll
  for (int ni = 0; ni < NI; ni++) {
    const int col = n0 + wc*(BN/4) + ni*16 + lane15;
    const float bv = bias ? bias[col] : 0.f;
    #pragma unroll
    for (int mi = 0; mi < 8; mi++) {
      #pragma unroll
      for (int r = 0; r < 4; r++) {
        const int row = m0 + wr*128 + mi*16 + lgrp*4 + r;
        float v = acc[mi][ni][r] + bv;
        if (EPI == 1) v = gelu_f(v);
        Cout[(size_t)row*N + col] = (short)f2bf(v);
      }
    }
  }
}

// ====== BM x 128 tile (BM = MT*32), BK=64, 4 waves, counted-vmcnt pipeline ==
// EPI: 1 = UG split: col<128 -> drive fp32[.][128]; col>=128 -> sigmoid bf16 gate
//      3 = RES: out = acc + bias + out  (fp32, in-place resid)
template<int MT, int EPI>
__global__ __launch_bounds__(256) void gemm128(
    const short* __restrict__ A, const short* __restrict__ Bt,
    const float* __restrict__ bias,
    short* __restrict__ e_g,
    void* __restrict__ Cout, int M, int N, int K)
{
  constexpr int BM  = MT * 32;
  constexpr int ABY = BM * 128;
  constexpr int STR = ABY + 16384;
  constexpr int MPQ = MT / 2;
  extern __shared__ char lds[];
  const int tid = threadIdx.x;
  const int ln = tid & 63, w = tid >> 6;
  const int wr = w >> 1, wc = w & 1;
  const int lane15 = ln & 15, lgrp = ln >> 4;

  const int gx = gridDim.x;
  const int nwg = gx * gridDim.y;
  int id = blockIdx.y * gx + blockIdx.x;
  if ((nwg & 7) == 0) { const int cpx = nwg >> 3; id = (id & 7) * cpx + (id >> 3); }
  const int m0 = (id / gx) * BM, n0 = (id % gx) * 128;

  const int NT = K >> 6;

  f32x4 acc[MT][4];
  #pragma unroll
  for (int i=0;i<MT;i++)
    #pragma unroll
    for (int j=0;j<4;j++) acc[i][j] = (f32x4){0.f,0.f,0.f,0.f};

  #define STG(k0_, bufA_, bufB_, p_) { \
    const int slot = (p_)*256 + tid; \
    const int row = slot >> 3, blk = slot & 7; \
    const int sblk = blk ^ (row & 7); \
    if ((p_) < MT) async16(A + (size_t)(m0+row)*K + (k0_) + sblk*8, (bufA_) + slot*16); \
    async16(Bt + (size_t)(n0+row)*K + (k0_) + sblk*8, (bufB_) + slot*16); }

  {
    char* bA = lds, *bB = lds + ABY;
    STG(0, bA, bB, 0); STG(0, bA, bB, 1); STG(0, bA, bB, 2); STG(0, bA, bB, 3);
    if (NT > 1) { char* cA = lds + STR, *cB = cA + ABY; STG(64, cA, cB, 0); }
    asm volatile("s_waitcnt vmcnt(0)" ::: "memory");
    __builtin_amdgcn_s_barrier();
    __builtin_amdgcn_sched_barrier(0);
  }

  for (int kt = 0; kt < NT; ++kt) {
    const int cur = kt & 1;
    char* rdA = lds + cur*STR;   char* rdB = rdA + ABY;
    char* wrA = lds + (cur^1)*STR; char* wrB = wrA + ABY;
    const int kn = (kt+1) << 6;
    bf16x8 bfr[4][2];
    #pragma unroll
    for (int ni = 0; ni < 4; ni++) {
      const int row = wc*64 + ni*16 + lane15;
      #pragma unroll
      for (int ks = 0; ks < 2; ks++) {
        const int b = (ks*4 + lgrp) ^ (row & 7);
        bfr[ni][ks] = *reinterpret_cast<const bf16x8*>(rdB + (row*8 + b)*16);
      }
    }
    if (kt+1 < NT) STG(kn, wrA, wrB, 1);
    #pragma unroll
    for (int mq = 0; mq < 2; ++mq) {
      bf16x8 af[MPQ][2];
      #pragma unroll
      for (int mi = 0; mi < MPQ; mi++) {
        const int row = wr*(MT*16) + (mq*MPQ+mi)*16 + lane15;
        #pragma unroll
        for (int ks = 0; ks < 2; ks++) {
          const int b = (ks*4 + lgrp) ^ (row & 7);
          af[mi][ks] = *reinterpret_cast<const bf16x8*>(rdA + (row*8 + b)*16);
        }
      }
      if (kt+1 < NT) STG(kn, wrA, wrB, 2+mq);
      #pragma unroll
      for (int mi = 0; mi < MPQ; mi++)
        #pragma unroll
        for (int ni = 0; ni < 4; ni++)
          #pragma unroll
          for (int ks = 0; ks < 2; ks++)
            acc[mq*MPQ+mi][ni] = __builtin_amdgcn_mfma_f32_16x16x32_bf16(
                af[mi][ks], bfr[ni][ks], acc[mq*MPQ+mi][ni], 0, 0, 0);
    }
    if (kt+1 < NT) {
      __builtin_amdgcn_s_barrier();
      if (kt+2 < NT) {
        STG((kt+2) << 6, rdA, rdB, 0);
        asm volatile("s_waitcnt vmcnt(2)" ::: "memory");
      } else {
        asm volatile("s_waitcnt vmcnt(0)" ::: "memory");
      }
      __builtin_amdgcn_s_barrier();
      __builtin_amdgcn_sched_barrier(0);
    }
  }
  #undef STG

  #pragma unroll
  for (int ni = 0; ni < 4; ni++) {
    const int col = n0 + wc*64 + ni*16 + lane15;
    const float bv = bias ? bias[col] : 0.f;
    #pragma unroll
    for (int mi = 0; mi < MT; mi++) {
      #pragma unroll
      for (int r = 0; r < 4; r++) {
        const int row = m0 + wr*(MT*16) + mi*16 + lgrp*4 + r;
        float v = acc[mi][ni][r] + bv;
        if (EPI == 1) {
          if (col < 128) ((float*)Cout)[(size_t)row*128 + col] = v;
          else {
            const float gs = 1.f/(1.f+__expf(-v));
            e_g[(size_t)row*1024 + col - 128] = (short)f2bf(gs);
          }
        } else {
          float* o = (float*)Cout;
          o[(size_t)row*N + col] = v + o[(size_t)row*N + col];
        }
      }
    }
  }
}

// ====== Fused W_O + C_w combine: out = x + g*(attn@WO+bO) + (1-g)*(st@Cw) ===
__global__ __launch_bounds__(256) void wo_comb(
    const short* __restrict__ A1, const short* __restrict__ B1t,
    const short* __restrict__ A2, const short* __restrict__ B2t,
    const float* __restrict__ bias, const float* __restrict__ e_x,
    const short* __restrict__ e_g, float* __restrict__ Cout)
{
  constexpr int ABY = 8192;
  constexpr int STR = ABY + 16384;
  extern __shared__ char lds[];
  const int tid = threadIdx.x;
  const int ln = tid & 63, w = tid >> 6;
  const int wr = w >> 1, wc = w & 1;
  const int lane15 = ln & 15, lgrp = ln >> 4;
  const int K = 1024, N = 1024;

  const int gx = gridDim.x;
  const int nwg = gx * gridDim.y;
  int id = blockIdx.y * gx + blockIdx.x;
  if ((nwg & 7) == 0) { const int cpx = nwg >> 3; id = (id & 7) * cpx + (id >> 3); }
  const int m0 = (id / gx) * 64, n0 = (id % gx) * 128;

  f32x4 acc1[2][4], acc2[2][4];
  #pragma unroll
  for (int i=0;i<2;i++)
    #pragma unroll
    for (int j=0;j<4;j++){ acc1[i][j] = (f32x4){0.f,0.f,0.f,0.f}; acc2[i][j] = (f32x4){0.f,0.f,0.f,0.f}; }

  #define STGW(Asrc_, Bsrc_, AK_, k0_, bufA_, bufB_, p_) { \
    const int slot = (p_)*256 + tid; \
    const int row = slot >> 3, blk = slot & 7; \
    const int sblk = blk ^ (row & 7); \
    if ((p_) < 2) async16(Asrc_ + (size_t)(m0+row)*(AK_) + (k0_) + sblk*8, (bufA_) + slot*16); \
    async16(Bsrc_ + (size_t)(n0+row)*(AK_) + (k0_) + sblk*8, (bufB_) + slot*16); }

  {
    char* bA = lds, *bB = lds + ABY;
    STGW(A1, B1t, K, 0, bA, bB, 0); STGW(A1, B1t, K, 0, bA, bB, 1);
    STGW(A1, B1t, K, 0, bA, bB, 2); STGW(A1, B1t, K, 0, bA, bB, 3);
    { char* cA = lds + STR, *cB = cA + ABY; STGW(A1, B1t, K, 64, cA, cB, 0); }
    asm volatile("s_waitcnt vmcnt(0)" ::: "memory");
    __builtin_amdgcn_s_barrier();
    __builtin_amdgcn_sched_barrier(0);
  }

  const int NT = 16;
  for (int kt = 0; kt < NT; ++kt) {
    const int cur = kt & 1;
    char* rdA = lds + cur*STR;   char* rdB = rdA + ABY;
    char* wrA = lds + (cur^1)*STR; char* wrB = wrA + ABY;
    const int kn = (kt+1) << 6;
    bf16x8 bfr[4][2];
    #pragma unroll
    for (int ni = 0; ni < 4; ni++) {
      const int row = wc*64 + ni*16 + lane15;
      #pragma unroll
      for (int ks = 0; ks < 2; ks++) {
        const int b = (ks*4 + lgrp) ^ (row & 7);
        bfr[ni][ks] = *reinterpret_cast<const bf16x8*>(rdB + (row*8 + b)*16);
      }
    }
    if (kt+1 < NT) STGW(A1, B1t, K, kn, wrA, wrB, 1);
    #pragma unroll
    for (int mq = 0; mq < 2; ++mq) {
      bf16x8 af[2];
      {
        const int row = wr*32 + mq*16 + lane15;
        #pragma unroll
        for (int ks = 0; ks < 2; ks++) {
          const int b = (ks*4 + lgrp) ^ (row & 7);
          af[ks] = *reinterpret_cast<const bf16x8*>(rdA + (row*8 + b)*16);
        }
      }
      if (kt+1 < NT) STGW(A1, B1t, K, kn, wrA, wrB, 2+mq);
      #pragma unroll
      for (int ni = 0; ni < 4; ni++)
        #pragma unroll
        for (int ks = 0; ks < 2; ks++)
          acc1[mq][ni] = __builtin_amdgcn_mfma_f32_16x16x32_bf16(
              af[ks], bfr[ni][ks], acc1[mq][ni], 0, 0, 0);
    }
    if (kt+1 < NT) {
      __builtin_amdgcn_s_barrier();
      if (kt+2 < NT) {
        STGW(A1, B1t, K, (kt+2) << 6, rdA, rdB, 0);
        asm volatile("s_waitcnt vmcnt(2)" ::: "memory");
      } else {
        asm volatile("s_waitcnt vmcnt(0)" ::: "memory");
      }
      __builtin_amdgcn_s_barrier();
      __builtin_amdgcn_sched_barrier(0);
    }
  }

  __builtin_amdgcn_s_barrier();
  {
    char* bA0 = lds,       *bB0 = lds + ABY;
    char* bA1 = lds + STR, *bB1 = bA1 + ABY;
    STGW(A2, B2t, 128, 0,  bA0, bB0, 0); STGW(A2, B2t, 128, 0,  bA0, bB0, 1);
    STGW(A2, B2t, 128, 0,  bA0, bB0, 2); STGW(A2, B2t, 128, 0,  bA0, bB0, 3);
    STGW(A2, B2t, 128, 64, bA1, bB1, 0); STGW(A2, B2t, 128, 64, bA1, bB1, 1);
    STGW(A2, B2t, 128, 64, bA1, bB1, 2); STGW(A2, B2t, 128, 64, bA1, bB1, 3);
    asm volatile("s_waitcnt vmcnt(0)" ::: "memory");
    __builtin_amdgcn_s_barrier();
  }
  #pragma unroll
  for (int t2 = 0; t2 < 2; ++t2) {
    char* rdA = lds + t2*STR; char* rdB = rdA + ABY;
    bf16x8 bfr2[4][2];
    #pragma unroll
    for (int ni = 0; ni < 4; ni++) {
      const int brow = wc*64 + ni*16 + lane15;
      #pragma unroll
      for (int ks = 0; ks < 2; ks++) {
        const int b = (ks*4 + lgrp) ^ (brow & 7);
        bfr2[ni][ks] = *reinterpret_cast<const bf16x8*>(rdB + (brow*8 + b)*16);
      }
    }
    #pragma unroll
    for (int mi = 0; mi < 2; mi++) {
      bf16x8 af[2];
      const int row = wr*32 + mi*16 + lane15;
      #pragma unroll
      for (int ks = 0; ks < 2; ks++) {
        const int b = (ks*4 + lgrp) ^ (row & 7);
        af[ks] = *reinterpret_cast<const bf16x8*>(rdA + (row*8 + b)*16);
      }
      #pragma unroll
      for (int ni = 0; ni < 4; ni++)
        #pragma unroll
        for (int ks = 0; ks < 2; ks++)
          acc2[mi][ni] = __builtin_amdgcn_mfma_f32_16x16x32_bf16(af[ks], bfr2[ni][ks], acc2[mi][ni], 0, 0, 0);
    }
  }
  #undef STGW

  #pragma unroll
  for (int ni = 0; ni < 4; ni++) {
    const int col = n0 + wc*64 + ni*16 + lane15;
    const float bv = bias[col];
    #pragma unroll
    for (int mi = 0; mi < 2; mi++) {
      #pragma unroll
      for (int r = 0; r < 4; r++) {
        const int row = m0 + wr*32 + mi*16 + lgrp*4 + r;
        const float g = bf2f(e_g[(size_t)row*1024 + col]);
        Cout[(size_t)row*N + col] = e_x[(size_t)row*1024 + col]
            + g*(acc1[mi][ni][r] + bv) + (1.f-g)*acc2[mi][ni][r];
      }
    }
  }
}

// ---------------- Flash sliding-window attention (MFMA, bf16) ---------------
#define ATS 72
__global__ __launch_bounds__(256) void attn_mfma(const short* __restrict__ qkv,
                                                 short* __restrict__ attn_out)
{
  __shared__ short Qs[64*ATS];
  __shared__ short Ks[64*ATS];
  __shared__ short Vt[64*ATS];
  __shared__ short Ps[4][16*ATS];
  const int tid = threadIdx.x;
  const int ln = tid & 63, w = tid >> 6;
  const int qt0 = (blockIdx.x >> 4) * 64;
  const int h = blockIdx.x & 15;

  {
    const int jr = tid >> 3, d0 = (tid & 7) * 8;
    #pragma unroll
    for (int p = 0; p < 2; p++) {
      const int j = jr + p*32;
      const bf16x8 v = *reinterpret_cast<const bf16x8*>(&qkv[(size_t)(qt0 + j)*3072 + h*64 + d0]);
      const int blk = (d0 >> 3) ^ (j & 7);
      *reinterpret_cast<bf16x8*>(&Qs[j*ATS + blk*8]) = v;
    }
  }

  float mrow[4], lrow[4];
  f32x4 oacc[4];
  #pragma unroll
  for (int r=0;r<4;r++){ mrow[r] = -1e30f; lrow[r] = 0.f; }
  #pragma unroll
  for (int df=0;df<4;df++) oacc[df] = (f32x4){0.f,0.f,0.f,0.f};

  const int qrow_lane = w*16 + (ln>>4)*4;
  const int qtile = qt0 >> 6;
  const int cstart = (qtile >= 4) ? 0 : (4 - qtile);

  for (int c = cstart; c < 5; c++) {
    const int cs = qt0 - 256 + c*64;
    {
      const int jr = tid >> 3, d0 = (tid & 7) * 8;
      #pragma unroll
      for (int p = 0; p < 2; p++) {
        const int j = jr + p*32;
        const size_t krow = (size_t)(cs + j)*3072 + h*64;
        const bf16x8 kv = *reinterpret_cast<const bf16x8*>(&qkv[krow + 1024 + d0]);
        const int blk = (d0>>3) ^ (j & 7);
        *reinterpret_cast<bf16x8*>(&Ks[j*ATS + blk*8]) = kv;
        const bf16x8 vv = *reinterpret_cast<const bf16x8*>(&qkv[krow + 2048 + d0]);
        #pragma unroll
        for (int i = 0; i < 8; i++) {
          const int d = d0 + i;
          const int jb = (j >> 3) ^ ((d >> 3) & 7);
          Vt[d*ATS + jb*8 + (j & 7)] = ((const short*)&vv)[i];
        }
      }
    }
    __syncthreads();

    bf16x8 aq[2];
    #pragma unroll
    for (int ks=0; ks<2; ks++){
      const int row = w*16 + (ln & 15);
      const int b = (ks*4 + (ln>>4)) ^ (row & 7);
      aq[ks] = *reinterpret_cast<const bf16x8*>(&Qs[row*ATS + b*8]);
    }
    float sv[4][4];
    #pragma unroll
    for (int nf=0; nf<4; nf++){
      const int krow = nf*16 + (ln & 15);
      f32x4 s = (f32x4){0.f,0.f,0.f,0.f};
      #pragma unroll
      for (int ks=0; ks<2; ks++){
        const int b = (ks*4 + (ln>>4)) ^ (krow & 7);
        const bf16x8 bk = *reinterpret_cast<const bf16x8*>(&Ks[krow*ATS + b*8]);
        s = __builtin_amdgcn_mfma_f32_16x16x32_bf16(aq[ks], bk, s, 0, 0, 0);
      }
      const int k_abs = cs + nf*16 + (ln & 15);
      #pragma unroll
      for (int r=0;r<4;r++){
        const int t_abs = qt0 + qrow_lane + r;
        const bool valid = (k_abs <= t_abs) && (k_abs >= t_abs - 255);
        sv[nf][r] = valid ? s[r]*0.125f : -1e30f;
      }
    }
    float cm[4], alpha[4], rs[4];
    #pragma unroll
    for (int r=0;r<4;r++){
      cm[r] = fmaxf(fmaxf(sv[0][r],sv[1][r]), fmaxf(sv[2][r],sv[3][r]));
      #pragma unroll
      for (int off=1; off<16; off<<=1) cm[r] = fmaxf(cm[r], __shfl_xor(cm[r], off));
      const float mnew = fmaxf(mrow[r], cm[r]);
      alpha[r] = __expf(mrow[r] - mnew);
      mrow[r] = mnew;
      rs[r] = 0.f;
    }
    #pragma unroll
    for (int nf=0; nf<4; nf++){
      const int pcol = nf*16 + (ln & 15);
      #pragma unroll
      for (int r=0;r<4;r++){
        const float p = (sv[nf][r] <= -1e29f) ? 0.f : __expf(sv[nf][r] - mrow[r]);
        rs[r] += p;
        const int prow = (ln>>4)*4 + r;
        const int pb = (pcol>>3) ^ (prow & 7);
        Ps[w][prow*ATS + pb*8 + (pcol & 7)] = (short)f2bf(p);
      }
    }
    #pragma unroll
    for (int r=0;r<4;r++){
      #pragma unroll
      for (int off=1; off<16; off<<=1) rs[r] += __shfl_xor(rs[r], off);
      lrow[r] = lrow[r]*alpha[r] + rs[r];
      #pragma unroll
      for (int df=0; df<4; df++) oacc[df][r] *= alpha[r];
    }
    bf16x8 ap[2];
    #pragma unroll
    for (int ks=0; ks<2; ks++){
      const int prow = (ln & 15);
      const int b = (ks*4 + (ln>>4)) ^ (prow & 7);
      ap[ks] = *reinterpret_cast<const bf16x8*>(&Ps[w][prow*ATS + b*8]);
    }
    #pragma unroll
    for (int df=0; df<4; df++){
      const int vrow = df*16 + (ln & 15);
      #pragma unroll
      for (int ks=0; ks<2; ks++){
        const int b = (ks*4 + (ln>>4)) ^ ((vrow>>3) & 7);
        const bf16x8 bv = *reinterpret_cast<const bf16x8*>(&Vt[vrow*ATS + b*8]);
        oacc[df] = __builtin_amdgcn_mfma_f32_16x16x32_bf16(ap[ks], bv, oacc[df], 0, 0, 0);
      }
    }
    __syncthreads();
  }

  #pragma unroll
  for (int df=0; df<4; df++)
    #pragma unroll
    for (int r=0; r<4; r++){
      const int t = qt0 + qrow_lane + r;
      const int d = df*16 + (ln & 15);
      attn_out[(size_t)t*1024 + h*64 + d] = (short)f2bf(oacc[df][r] / lrow[r]);
    }
}

// ---------------- SSM scan as 16-tap convolution (compact drive) ------------
__global__ __launch_bounds__(256) void scan_kernel(const float* __restrict__ drive,
    const float* __restrict__ Aa, short* __restrict__ states)
{
  const int idx = blockIdx.x*256 + threadIdx.x;
  const int t = idx >> 7, s = idx & 127;
  const float a = Aa[s];
  float acc = 0.f, pw = 1.f;
  const int kmax = (t+1 < 16) ? (t+1) : 16;
  for (int k=0;k<kmax;k++){
    acc = fmaf(pw, drive[(size_t)(t-k)*128 + s], acc);
    pw *= a;
  }
  states[idx] = (short)f2bf(acc);
}

extern "C" void kernel_launch(void* const* d_in, const int* in_sizes, int n_in,
                              void* d_out, int out_size, void* d_ws, size_t ws_size,
                              hipStream_t stream)
{
  const float* x     = (const float*)d_in[0];
  const float* ln1_g = (const float*)d_in[1];
  const float* ln1_b = (const float*)d_in[2];
  const float* ln2_g = (const float*)d_in[3];
  const float* ln2_b = (const float*)d_in[4];
  const float* W_qkv = (const float*)d_in[5];
  const float* W_O   = (const float*)d_in[6];
  const float* b_O   = (const float*)d_in[7];
  const float* W_ug  = (const float*)d_in[8];
  const float* b_ug  = (const float*)d_in[9];
  const float* B_w   = (const float*)d_in[10];
  const float* A     = (const float*)d_in[11];
  const float* C_w   = (const float*)d_in[12];
  const float* W1    = (const float*)d_in[13];
  const float* b1    = (const float*)d_in[14];
  const float* W2    = (const float*)d_in[15];
  const float* b2    = (const float*)d_in[16];
  float* out = (float*)d_out;
  char* ws = (char*)d_ws;

  short* qkv_bf = (short*)(ws + 0);          // 24MB
  short* attn_bf= (short*)(ws + 25165824);   // 8MB
  short* xn_bf  = (short*)(ws + 33554432);   // 8MB (h aliases)
  short* g_bf   = (short*)(ws + 41943040);   // 8MB
  float* drive  = (float*)(ws + 50331648);   // 2MB
  short* st_bf  = (short*)(ws + 52428800);   // 1MB
  short* wT_qkv = (short*)(ws + 53542912);   // 6MB
  short* wT_o   = (short*)(ws + 59834368);   // 2MB
  short* wT_ug  = (short*)(ws + 61931520);   // 2.25MB
  short* wT_c   = (short*)(ws + 64290816);   // 0.25MB
  short* wT_1   = (short*)(ws + 64552960);   // 8MB
  short* wT_2   = (short*)(ws + 72941568);   // 8MB
  short* mid_bf = (short*)(ws + 0);          // 32MB alias (dead qkv+attn)
  short* h_bf   = xn_bf;

  static bool attr_done = false;
  if (!attr_done) {
    hipFuncSetAttribute((const void*)(gemm256<192,0>), hipFuncAttributeMaxDynamicSharedMemorySize, 114688);
    hipFuncSetAttribute((const void*)(gemm256<256,1>), hipFuncAttributeMaxDynamicSharedMemorySize, 131072);
    hipFuncSetAttribute((const void*)(gemm128<2,1>), hipFuncAttributeMaxDynamicSharedMemorySize, 49152);
    hipFuncSetAttribute((const void*)(gemm128<2,3>), hipFuncAttributeMaxDynamicSharedMemorySize, 49152);
    hipFuncSetAttribute((const void*)wo_comb, hipFuncAttributeMaxDynamicSharedMemorySize, 49152);
    attr_done = true;
  }

  prep_weights<<<13568, 256, 0, stream>>>(W_qkv, W_O, W_ug, B_w, C_w, W1, W2,
                                          wT_qkv, wT_o, wT_ug, wT_c, wT_1, wT_2);

  ln_bf16<<<4096, 256, 0, stream>>>(x, ln1_g, ln1_b, xn_bf);
  // qkv: 256x192 tiles -> grid (16,16) = 256 blocks, all CUs busy
  gemm256<192,0><<<dim3(16,16), 512, 114688, stream>>>(xn_bf, wT_qkv, nullptr, qkv_bf, 4096, 3072, 1024);
  attn_mfma<<<1024, 256, 0, stream>>>(qkv_bf, attn_bf);
  gemm128<2,1><<<dim3(9,64), 256, 49152, stream>>>(xn_bf, wT_ug, b_ug, g_bf, drive, 4096, 1152, 1024);
  scan_kernel<<<2048, 256, 0, stream>>>(drive, A, st_bf);
  wo_comb<<<dim3(8,64), 256, 49152, stream>>>(attn_bf, wT_o, st_bf, wT_c, b_O, x, g_bf, out);
  ln_bf16<<<4096, 256, 0, stream>>>(out, ln2_g, ln2_b, h_bf);
  gemm256<256,1><<<dim3(16,16), 512, 131072, stream>>>(h_bf, wT_1, b1, mid_bf, 4096, 4096, 1024);
  gemm128<2,3><<<dim3(8,64), 256, 49152, stream>>>(mid_bf, wT_2, b2, nullptr, out, 4096, 1024, 4096);
}

// Round 18
// 237.128 us; speedup vs baseline: 1.0685x; 1.0112x over previous
//
#include <hip/hip_runtime.h>
#include <hip/hip_bf16.h>
#include <math.h>

typedef short bf16x8 __attribute__((ext_vector_type(8)));
typedef float f32x4  __attribute__((ext_vector_type(4)));

#define GLOBAL_AS __attribute__((address_space(1)))
#define LDS_AS    __attribute__((address_space(3)))

__device__ __forceinline__ void async16(const void* g, void* l) {
  __builtin_amdgcn_global_load_lds((GLOBAL_AS void*)(g), (LDS_AS void*)(l), 16, 0, 0);
}

__device__ __forceinline__ unsigned short f2bf(float f){
  union { float f; unsigned u; } x; x.f = f;
  return (unsigned short)((x.u + 0x7fffu + ((x.u >> 16) & 1u)) >> 16);
}
__device__ __forceinline__ float bf2f(short s){
  union { unsigned u; float f; } x; x.u = ((unsigned)(unsigned short)s) << 16;
  return x.f;
}
__device__ __forceinline__ float gelu_f(float x){
  return 0.5f*x*(1.f+erff(x*0.70710678118654752f));
}

// ---------------- LayerNorm body (one row per block) ------------------------
__device__ __forceinline__ void ln_body(const float* __restrict__ in,
    const float* __restrict__ gg, const float* __restrict__ bb,
    short* __restrict__ out, int row)
{
  const int tid = threadIdx.x;
  const float4 v = reinterpret_cast<const float4*>(in + (size_t)row*1024)[tid];
  float s  = v.x+v.y+v.z+v.w;
  float sq = v.x*v.x+v.y*v.y+v.z*v.z+v.w*v.w;
  #pragma unroll
  for (int off=32; off; off>>=1){ s += __shfl_xor(s,off); sq += __shfl_xor(sq,off); }
  __shared__ float ss[4], qs[4];
  const int wid = tid>>6, lane = tid&63;
  if (lane==0){ ss[wid]=s; qs[wid]=sq; }
  __syncthreads();
  s  = ss[0]+ss[1]+ss[2]+ss[3];
  sq = qs[0]+qs[1]+qs[2]+qs[3];
  const float mu  = s * (1.f/1024.f);
  const float var = sq*(1.f/1024.f) - mu*mu;
  const float rs  = rsqrtf(var + 1e-5f);
  const float4 g4 = reinterpret_cast<const float4*>(gg)[tid];
  const float4 b4 = reinterpret_cast<const float4*>(bb)[tid];
  ushort4 o;
  o.x = f2bf((v.x-mu)*rs*g4.x+b4.x);
  o.y = f2bf((v.y-mu)*rs*g4.y+b4.y);
  o.z = f2bf((v.z-mu)*rs*g4.z+b4.z);
  o.w = f2bf((v.w-mu)*rs*g4.w+b4.w);
  *reinterpret_cast<ushort4*>(out + (size_t)row*1024 + tid*4) = o;
}

__global__ __launch_bounds__(256) void ln_bf16(const float* __restrict__ in,
    const float* __restrict__ gg, const float* __restrict__ bb, short* __restrict__ out)
{
  ln_body(in, gg, bb, out, blockIdx.x);
}

// ------ fused prep: all weight transposes + LN1 in one launch ---------------
__device__ __forceinline__ void conv_body(const float* __restrict__ in,
    short* __restrict__ out, int K, int N, const float* __restrict__ add, int addN,
    int bx, int by)
{
  __shared__ float tile[32][33];
  const int n0 = bx*32, k0 = by*32;
  const int r = threadIdx.x >> 3, c4 = (threadIdx.x & 7)*4;
  float4 v = *reinterpret_cast<const float4*>(&in[(size_t)(k0+r)*N + n0 + c4]);
  if (add && (n0 + c4) < addN) {
    const float* ap = &add[(size_t)(k0+r)*addN + n0 + c4];
    v.x += ap[0]; v.y += ap[1]; v.z += ap[2]; v.w += ap[3];
  }
  tile[r][c4+0]=v.x; tile[r][c4+1]=v.y; tile[r][c4+2]=v.z; tile[r][c4+3]=v.w;
  __syncthreads();
  ushort4 o;
  o.x = f2bf(tile[c4+0][r]); o.y = f2bf(tile[c4+1][r]);
  o.z = f2bf(tile[c4+2][r]); o.w = f2bf(tile[c4+3][r]);
  *reinterpret_cast<ushort4*>(&out[(size_t)(n0+r)*K + k0 + c4]) = o;
}

__global__ __launch_bounds__(256) void prep_weights(
    const float* __restrict__ W_qkv, const float* __restrict__ W_O,
    const float* __restrict__ W_ug,  const float* __restrict__ B_w,
    const float* __restrict__ C_w,   const float* __restrict__ W1,
    const float* __restrict__ W2,
    const float* __restrict__ x,     const float* __restrict__ ln1_g,
    const float* __restrict__ ln1_b,
    short* __restrict__ wT_qkv, short* __restrict__ wT_o,
    short* __restrict__ wT_ug,  short* __restrict__ wT_c,
    short* __restrict__ wT_1,   short* __restrict__ wT_2,
    short* __restrict__ xn_bf)
{
  const int bid = blockIdx.x;
  if (bid < 3072) {
    conv_body(W_qkv, wT_qkv, 1024, 3072, nullptr, 0, bid % 96, bid / 96);
  } else if (bid < 4224) {
    const int j = bid - 3072;
    conv_body(W_ug, wT_ug, 1024, 1152, B_w, 128, j % 36, j / 36);
  } else if (bid < 5248) {
    const int j = bid - 4224;
    conv_body(W_O, wT_o, 1024, 1024, nullptr, 0, j % 32, j / 32);
  } else if (bid < 5376) {
    const int j = bid - 5248;
    conv_body(C_w, wT_c, 128, 1024, nullptr, 0, j % 32, j / 32);
  } else if (bid < 9472) {
    const int j = bid - 5376;
    conv_body(W1, wT_1, 1024, 4096, nullptr, 0, j % 128, j / 128);
  } else if (bid < 13568) {
    const int j = bid - 9472;
    conv_body(W2, wT_2, 4096, 1024, nullptr, 0, j % 32, j / 32);
  } else {
    ln_body(x, ln1_g, ln1_b, xn_bf, bid - 13568);   // LN1: 4096 rows
  }
}

// ======== 256 x BN tile, BK=64, 8 waves (2x4), counted-vmcnt pipeline =======
// BN in {192, 256}. EPI: 0 = plain -> bf16 out, 1 = bias+gelu -> bf16 out.
template<int BN, int EPI>
__global__ __launch_bounds__(512) void gemm256(
    const short* __restrict__ A, const short* __restrict__ Bt,
    const float* __restrict__ bias, short* __restrict__ Cout,
    int M, int N, int K)
{
  constexpr int NI  = BN / 64;
  constexpr int NB  = BN / 64;
  constexpr int BBY = BN * 128;
  constexpr int STR = 32768 + BBY;
  extern __shared__ char lds[];
  const int tid = threadIdx.x;
  const int ln = tid & 63, w = tid >> 6;
  const int wr = w >> 2, wc = w & 3;
  const int lane15 = ln & 15, lgrp = ln >> 4;

  const int gx = gridDim.x;
  const int nwg = gx * gridDim.y;
  int id = blockIdx.y * gx + blockIdx.x;
  if ((nwg & 7) == 0) { const int cpx = nwg >> 3; id = (id & 7) * cpx + (id >> 3); }
  const int m0 = (id / gx) * 256, n0 = (id % gx) * BN;

  const int NT = K >> 6;

  f32x4 acc[8][NI];
  #pragma unroll
  for (int i=0;i<8;i++)
    #pragma unroll
    for (int j=0;j<NI;j++) acc[i][j] = (f32x4){0.f,0.f,0.f,0.f};

  #define STGA(k0_, buf_, p_) { \
    const int slot = (p_)*512 + tid; \
    const int row = slot >> 3, blk = slot & 7; \
    const int sblk = blk ^ (row & 7); \
    async16(A + (size_t)(m0+row)*K + (k0_) + sblk*8, (buf_) + slot*16); }

  #define STGB(k0_, buf_, p_) { \
    const int slot = (p_)*512 + tid; \
    const int row = slot >> 3, blk = slot & 7; \
    const int sblk = blk ^ (row & 7); \
    async16(Bt + (size_t)(n0+row)*K + (k0_) + sblk*8, (buf_) + 32768 + slot*16); }

  {
    char* b0 = lds;
    STGA(0, b0, 0); STGA(0, b0, 1); STGA(0, b0, 2); STGA(0, b0, 3);
    #pragma unroll
    for (int p = 0; p < NB; p++) STGB(0, b0, p);
    if (NT > 1) { char* b1 = lds + STR; STGA(64, b1, 0); STGB(64, b1, 0); }
    asm volatile("s_waitcnt vmcnt(0)" ::: "memory");
    __builtin_amdgcn_s_barrier();
    __builtin_amdgcn_sched_barrier(0);
  }

  for (int kt = 0; kt < NT; ++kt) {
    const int cur = kt & 1;
    char* rdbuf = lds + cur*STR;
    char* rdA = rdbuf; char* rdB = rdbuf + 32768;
    char* wrbuf = lds + (cur^1)*STR;
    const int kn = (kt+1) << 6;
    bf16x8 bfr[NI][2];
    #pragma unroll
    for (int ni = 0; ni < NI; ni++) {
      const int row = wc*(BN/4) + ni*16 + lane15;
      #pragma unroll
      for (int ks = 0; ks < 2; ks++) {
        const int b = (ks*4 + lgrp) ^ (row & 7);
        bfr[ni][ks] = *reinterpret_cast<const bf16x8*>(rdB + (row*8 + b)*16);
      }
    }
    if (kt+1 < NT) {
      STGA(kn, wrbuf, 3);
      #pragma unroll
      for (int p = 1; p < NB; p++) STGB(kn, wrbuf, p);
    }
    #pragma unroll
    for (int mq = 0; mq < 2; ++mq) {
      bf16x8 af[4][2];
      #pragma unroll
      for (int mi = 0; mi < 4; mi++) {
        const int row = wr*128 + (mq*4+mi)*16 + lane15;
        #pragma unroll
        for (int ks = 0; ks < 2; ks++) {
          const int b = (ks*4 + lgrp) ^ (row & 7);
          af[mi][ks] = *reinterpret_cast<const bf16x8*>(rdA + (row*8 + b)*16);
        }
      }
      if (kt+1 < NT) STGA(kn, wrbuf, 1+mq);
      #pragma unroll
      for (int mi = 0; mi < 4; mi++)
        #pragma unroll
        for (int ni = 0; ni < NI; ni++)
          #pragma unroll
          for (int ks = 0; ks < 2; ks++)
            acc[mq*4+mi][ni] = __builtin_amdgcn_mfma_f32_16x16x32_bf16(
                af[mi][ks], bfr[ni][ks], acc[mq*4+mi][ni], 0, 0, 0);
    }
    if (kt+1 < NT) {
      __builtin_amdgcn_s_barrier();
      if (kt+2 < NT) {
        STGA((kt+2) << 6, rdbuf, 0);
        STGB((kt+2) << 6, rdbuf, 0);
        asm volatile("s_waitcnt vmcnt(2)" ::: "memory");
      } else {
        asm volatile("s_waitcnt vmcnt(0)" ::: "memory");
      }
      __builtin_amdgcn_s_barrier();
      __builtin_amdgcn_sched_barrier(0);
    }
  }
  #undef STGA
  #undef STGB

  #pragma unroll
  for (int ni = 0; ni < NI; ni++) {
    const int col = n0 + wc*(BN/4) + ni*16 + lane15;
    const float bv = bias ? bias[col] : 0.f;
    #pragma unroll
    for (int mi = 0; mi < 8; mi++) {
      #pragma unroll
      for (int r = 0; r < 4; r++) {
        const int row = m0 + wr*128 + mi*16 + lgrp*4 + r;
        float v = acc[mi][ni][r] + bv;
        if (EPI == 1) v = gelu_f(v);
        Cout[(size_t)row*N + col] = (short)f2bf(v);
      }
    }
  }
}

// ====== BM x 128 tile (BM = MT*32), BK=64, 4 waves, counted-vmcnt pipeline ==
// EPI: 1 = UG split; 3 = RES fp32 in-place
template<int MT, int EPI>
__global__ __launch_bounds__(256) void gemm128(
    const short* __restrict__ A, const short* __restrict__ Bt,
    const float* __restrict__ bias,
    short* __restrict__ e_g,
    void* __restrict__ Cout, int M, int N, int K)
{
  constexpr int BM  = MT * 32;
  constexpr int ABY = BM * 128;
  constexpr int STR = ABY + 16384;
  constexpr int MPQ = MT / 2;
  extern __shared__ char lds[];
  const int tid = threadIdx.x;
  const int ln = tid & 63, w = tid >> 6;
  const int wr = w >> 1, wc = w & 1;
  const int lane15 = ln & 15, lgrp = ln >> 4;

  const int gx = gridDim.x;
  const int nwg = gx * gridDim.y;
  int id = blockIdx.y * gx + blockIdx.x;
  if ((nwg & 7) == 0) { const int cpx = nwg >> 3; id = (id & 7) * cpx + (id >> 3); }
  const int m0 = (id / gx) * BM, n0 = (id % gx) * 128;

  const int NT = K >> 6;

  f32x4 acc[MT][4];
  #pragma unroll
  for (int i=0;i<MT;i++)
    #pragma unroll
    for (int j=0;j<4;j++) acc[i][j] = (f32x4){0.f,0.f,0.f,0.f};

  #define STG(k0_, bufA_, bufB_, p_) { \
    const int slot = (p_)*256 + tid; \
    const int row = slot >> 3, blk = slot & 7; \
    const int sblk = blk ^ (row & 7); \
    if ((p_) < MT) async16(A + (size_t)(m0+row)*K + (k0_) + sblk*8, (bufA_) + slot*16); \
    async16(Bt + (size_t)(n0+row)*K + (k0_) + sblk*8, (bufB_) + slot*16); }

  {
    char* bA = lds, *bB = lds + ABY;
    STG(0, bA, bB, 0); STG(0, bA, bB, 1); STG(0, bA, bB, 2); STG(0, bA, bB, 3);
    if (NT > 1) { char* cA = lds + STR, *cB = cA + ABY; STG(64, cA, cB, 0); }
    asm volatile("s_waitcnt vmcnt(0)" ::: "memory");
    __builtin_amdgcn_s_barrier();
    __builtin_amdgcn_sched_barrier(0);
  }

  for (int kt = 0; kt < NT; ++kt) {
    const int cur = kt & 1;
    char* rdA = lds + cur*STR;   char* rdB = rdA + ABY;
    char* wrA = lds + (cur^1)*STR; char* wrB = wrA + ABY;
    const int kn = (kt+1) << 6;
    bf16x8 bfr[4][2];
    #pragma unroll
    for (int ni = 0; ni < 4; ni++) {
      const int row = wc*64 + ni*16 + lane15;
      #pragma unroll
      for (int ks = 0; ks < 2; ks++) {
        const int b = (ks*4 + lgrp) ^ (row & 7);
        bfr[ni][ks] = *reinterpret_cast<const bf16x8*>(rdB + (row*8 + b)*16);
      }
    }
    if (kt+1 < NT) STG(kn, wrA, wrB, 1);
    #pragma unroll
    for (int mq = 0; mq < 2; ++mq) {
      bf16x8 af[MPQ][2];
      #pragma unroll
      for (int mi = 0; mi < MPQ; mi++) {
        const int row = wr*(MT*16) + (mq*MPQ+mi)*16 + lane15;
        #pragma unroll
        for (int ks = 0; ks < 2; ks++) {
          const int b = (ks*4 + lgrp) ^ (row & 7);
          af[mi][ks] = *reinterpret_cast<const bf16x8*>(rdA + (row*8 + b)*16);
        }
      }
      if (kt+1 < NT) STG(kn, wrA, wrB, 2+mq);
      #pragma unroll
      for (int mi = 0; mi < MPQ; mi++)
        #pragma unroll
        for (int ni = 0; ni < 4; ni++)
          #pragma unroll
          for (int ks = 0; ks < 2; ks++)
            acc[mq*MPQ+mi][ni] = __builtin_amdgcn_mfma_f32_16x16x32_bf16(
                af[mi][ks], bfr[ni][ks], acc[mq*MPQ+mi][ni], 0, 0, 0);
    }
    if (kt+1 < NT) {
      __builtin_amdgcn_s_barrier();
      if (kt+2 < NT) {
        STG((kt+2) << 6, rdA, rdB, 0);
        asm volatile("s_waitcnt vmcnt(2)" ::: "memory");
      } else {
        asm volatile("s_waitcnt vmcnt(0)" ::: "memory");
      }
      __builtin_amdgcn_s_barrier();
      __builtin_amdgcn_sched_barrier(0);
    }
  }
  #undef STG

  #pragma unroll
  for (int ni = 0; ni < 4; ni++) {
    const int col = n0 + wc*64 + ni*16 + lane15;
    const float bv = bias ? bias[col] : 0.f;
    #pragma unroll
    for (int mi = 0; mi < MT; mi++) {
      #pragma unroll
      for (int r = 0; r < 4; r++) {
        const int row = m0 + wr*(MT*16) + mi*16 + lgrp*4 + r;
        float v = acc[mi][ni][r] + bv;
        if (EPI == 1) {
          if (col < 128) ((float*)Cout)[(size_t)row*128 + col] = v;
          else {
            const float gs = 1.f/(1.f+__expf(-v));
            e_g[(size_t)row*1024 + col - 128] = (short)f2bf(gs);
          }
        } else {
          float* o = (float*)Cout;
          o[(size_t)row*N + col] = v + o[(size_t)row*N + col];
        }
      }
    }
  }
}

// ====== Fused W_O + C_w combine: out = x + g*(attn@WO+bO) + (1-g)*(st@Cw) ===
__global__ __launch_bounds__(256) void wo_comb(
    const short* __restrict__ A1, const short* __restrict__ B1t,
    const short* __restrict__ A2, const short* __restrict__ B2t,
    const float* __restrict__ bias, const float* __restrict__ e_x,
    const short* __restrict__ e_g, float* __restrict__ Cout)
{
  constexpr int ABY = 8192;
  constexpr int STR = ABY + 16384;
  extern __shared__ char lds[];
  const int tid = threadIdx.x;
  const int ln = tid & 63, w = tid >> 6;
  const int wr = w >> 1, wc = w & 1;
  const int lane15 = ln & 15, lgrp = ln >> 4;
  const int K = 1024, N = 1024;

  const int gx = gridDim.x;
  const int nwg = gx * gridDim.y;
  int id = blockIdx.y * gx + blockIdx.x;
  if ((nwg & 7) == 0) { const int cpx = nwg >> 3; id = (id & 7) * cpx + (id >> 3); }
  const int m0 = (id / gx) * 64, n0 = (id % gx) * 128;

  f32x4 acc1[2][4], acc2[2][4];
  #pragma unroll
  for (int i=0;i<2;i++)
    #pragma unroll
    for (int j=0;j<4;j++){ acc1[i][j] = (f32x4){0.f,0.f,0.f,0.f}; acc2[i][j] = (f32x4){0.f,0.f,0.f,0.f}; }

  #define STGW(Asrc_, Bsrc_, AK_, k0_, bufA_, bufB_, p_) { \
    const int slot = (p_)*256 + tid; \
    const int row = slot >> 3, blk = slot & 7; \
    const int sblk = blk ^ (row & 7); \
    if ((p_) < 2) async16(Asrc_ + (size_t)(m0+row)*(AK_) + (k0_) + sblk*8, (bufA_) + slot*16); \
    async16(Bsrc_ + (size_t)(n0+row)*(AK_) + (k0_) + sblk*8, (bufB_) + slot*16); }

  {
    char* bA = lds, *bB = lds + ABY;
    STGW(A1, B1t, K, 0, bA, bB, 0); STGW(A1, B1t, K, 0, bA, bB, 1);
    STGW(A1, B1t, K, 0, bA, bB, 2); STGW(A1, B1t, K, 0, bA, bB, 3);
    { char* cA = lds + STR, *cB = cA + ABY; STGW(A1, B1t, K, 64, cA, cB, 0); }
    asm volatile("s_waitcnt vmcnt(0)" ::: "memory");
    __builtin_amdgcn_s_barrier();
    __builtin_amdgcn_sched_barrier(0);
  }

  const int NT = 16;
  for (int kt = 0; kt < NT; ++kt) {
    const int cur = kt & 1;
    char* rdA = lds + cur*STR;   char* rdB = rdA + ABY;
    char* wrA = lds + (cur^1)*STR; char* wrB = wrA + ABY;
    const int kn = (kt+1) << 6;
    bf16x8 bfr[4][2];
    #pragma unroll
    for (int ni = 0; ni < 4; ni++) {
      const int row = wc*64 + ni*16 + lane15;
      #pragma unroll
      for (int ks = 0; ks < 2; ks++) {
        const int b = (ks*4 + lgrp) ^ (row & 7);
        bfr[ni][ks] = *reinterpret_cast<const bf16x8*>(rdB + (row*8 + b)*16);
      }
    }
    if (kt+1 < NT) STGW(A1, B1t, K, kn, wrA, wrB, 1);
    #pragma unroll
    for (int mq = 0; mq < 2; ++mq) {
      bf16x8 af[2];
      {
        const int row = wr*32 + mq*16 + lane15;
        #pragma unroll
        for (int ks = 0; ks < 2; ks++) {
          const int b = (ks*4 + lgrp) ^ (row & 7);
          af[ks] = *reinterpret_cast<const bf16x8*>(rdA + (row*8 + b)*16);
        }
      }
      if (kt+1 < NT) STGW(A1, B1t, K, kn, wrA, wrB, 2+mq);
      #pragma unroll
      for (int ni = 0; ni < 4; ni++)
        #pragma unroll
        for (int ks = 0; ks < 2; ks++)
          acc1[mq][ni] = __builtin_amdgcn_mfma_f32_16x16x32_bf16(
              af[ks], bfr[ni][ks], acc1[mq][ni], 0, 0, 0);
    }
    if (kt+1 < NT) {
      __builtin_amdgcn_s_barrier();
      if (kt+2 < NT) {
        STGW(A1, B1t, K, (kt+2) << 6, rdA, rdB, 0);
        asm volatile("s_waitcnt vmcnt(2)" ::: "memory");
      } else {
        asm volatile("s_waitcnt vmcnt(0)" ::: "memory");
      }
      __builtin_amdgcn_s_barrier();
      __builtin_amdgcn_sched_barrier(0);
    }
  }

  __builtin_amdgcn_s_barrier();
  {
    char* bA0 = lds,       *bB0 = lds + ABY;
    char* bA1 = lds + STR, *bB1 = bA1 + ABY;
    STGW(A2, B2t, 128, 0,  bA0, bB0, 0); STGW(A2, B2t, 128, 0,  bA0, bB0, 1);
    STGW(A2, B2t, 128, 0,  bA0, bB0, 2); STGW(A2, B2t, 128, 0,  bA0, bB0, 3);
    STGW(A2, B2t, 128, 64, bA1, bB1, 0); STGW(A2, B2t, 128, 64, bA1, bB1, 1);
    STGW(A2, B2t, 128, 64, bA1, bB1, 2); STGW(A2, B2t, 128, 64, bA1, bB1, 3);
    asm volatile("s_waitcnt vmcnt(0)" ::: "memory");
    __builtin_amdgcn_s_barrier();
  }
  #pragma unroll
  for (int t2 = 0; t2 < 2; ++t2) {
    char* rdA = lds + t2*STR; char* rdB = rdA + ABY;
    bf16x8 bfr2[4][2];
    #pragma unroll
    for (int ni = 0; ni < 4; ni++) {
      const int brow = wc*64 + ni*16 + lane15;
      #pragma unroll
      for (int ks = 0; ks < 2; ks++) {
        const int b = (ks*4 + lgrp) ^ (brow & 7);
        bfr2[ni][ks] = *reinterpret_cast<const bf16x8*>(rdB + (brow*8 + b)*16);
      }
    }
    #pragma unroll
    for (int mi = 0; mi < 2; mi++) {
      bf16x8 af[2];
      const int row = wr*32 + mi*16 + lane15;
      #pragma unroll
      for (int ks = 0; ks < 2; ks++) {
        const int b = (ks*4 + lgrp) ^ (row & 7);
        af[ks] = *reinterpret_cast<const bf16x8*>(rdA + (row*8 + b)*16);
      }
      #pragma unroll
      for (int ni = 0; ni < 4; ni++)
        #pragma unroll
        for (int ks = 0; ks < 2; ks++)
          acc2[mi][ni] = __builtin_amdgcn_mfma_f32_16x16x32_bf16(af[ks], bfr2[ni][ks], acc2[mi][ni], 0, 0, 0);
    }
  }
  #undef STGW

  #pragma unroll
  for (int ni = 0; ni < 4; ni++) {
    const int col = n0 + wc*64 + ni*16 + lane15;
    const float bv = bias[col];
    #pragma unroll
    for (int mi = 0; mi < 2; mi++) {
      #pragma unroll
      for (int r = 0; r < 4; r++) {
        const int row = m0 + wr*32 + mi*16 + lgrp*4 + r;
        const float g = bf2f(e_g[(size_t)row*1024 + col]);
        Cout[(size_t)row*N + col] = e_x[(size_t)row*1024 + col]
            + g*(acc1[mi][ni][r] + bv) + (1.f-g)*acc2[mi][ni][r];
      }
    }
  }
}

// ---------------- Flash sliding-window attention (MFMA, bf16) ---------------
#define ATS 72
__global__ __launch_bounds__(256) void attn_mfma(const short* __restrict__ qkv,
                                                 short* __restrict__ attn_out)
{
  __shared__ short Qs[64*ATS];
  __shared__ short Ks[64*ATS];
  __shared__ short Vt[64*ATS];
  __shared__ short Ps[4][16*ATS];
  const int tid = threadIdx.x;
  const int ln = tid & 63, w = tid >> 6;
  const int qt0 = (blockIdx.x >> 4) * 64;
  const int h = blockIdx.x & 15;

  {
    const int jr = tid >> 3, d0 = (tid & 7) * 8;
    #pragma unroll
    for (int p = 0; p < 2; p++) {
      const int j = jr + p*32;
      const bf16x8 v = *reinterpret_cast<const bf16x8*>(&qkv[(size_t)(qt0 + j)*3072 + h*64 + d0]);
      const int blk = (d0 >> 3) ^ (j & 7);
      *reinterpret_cast<bf16x8*>(&Qs[j*ATS + blk*8]) = v;
    }
  }

  float mrow[4], lrow[4];
  f32x4 oacc[4];
  #pragma unroll
  for (int r=0;r<4;r++){ mrow[r] = -1e30f; lrow[r] = 0.f; }
  #pragma unroll
  for (int df=0;df<4;df++) oacc[df] = (f32x4){0.f,0.f,0.f,0.f};

  const int qrow_lane = w*16 + (ln>>4)*4;
  const int qtile = qt0 >> 6;
  const int cstart = (qtile >= 4) ? 0 : (4 - qtile);

  for (int c = cstart; c < 5; c++) {
    const int cs = qt0 - 256 + c*64;
    {
      const int jr = tid >> 3, d0 = (tid & 7) * 8;
      #pragma unroll
      for (int p = 0; p < 2; p++) {
        const int j = jr + p*32;
        const size_t krow = (size_t)(cs + j)*3072 + h*64;
        const bf16x8 kv = *reinterpret_cast<const bf16x8*>(&qkv[krow + 1024 + d0]);
        const int blk = (d0>>3) ^ (j & 7);
        *reinterpret_cast<bf16x8*>(&Ks[j*ATS + blk*8]) = kv;
        const bf16x8 vv = *reinterpret_cast<const bf16x8*>(&qkv[krow + 2048 + d0]);
        #pragma unroll
        for (int i = 0; i < 8; i++) {
          const int d = d0 + i;
          const int jb = (j >> 3) ^ ((d >> 3) & 7);
          Vt[d*ATS + jb*8 + (j & 7)] = ((const short*)&vv)[i];
        }
      }
    }
    __syncthreads();

    bf16x8 aq[2];
    #pragma unroll
    for (int ks=0; ks<2; ks++){
      const int row = w*16 + (ln & 15);
      const int b = (ks*4 + (ln>>4)) ^ (row & 7);
      aq[ks] = *reinterpret_cast<const bf16x8*>(&Qs[row*ATS + b*8]);
    }
    float sv[4][4];
    #pragma unroll
    for (int nf=0; nf<4; nf++){
      const int krow = nf*16 + (ln & 15);
      f32x4 s = (f32x4){0.f,0.f,0.f,0.f};
      #pragma unroll
      for (int ks=0; ks<2; ks++){
        const int b = (ks*4 + (ln>>4)) ^ (krow & 7);
        const bf16x8 bk = *reinterpret_cast<const bf16x8*>(&Ks[krow*ATS + b*8]);
        s = __builtin_amdgcn_mfma_f32_16x16x32_bf16(aq[ks], bk, s, 0, 0, 0);
      }
      const int k_abs = cs + nf*16 + (ln & 15);
      #pragma unroll
      for (int r=0;r<4;r++){
        const int t_abs = qt0 + qrow_lane + r;
        const bool valid = (k_abs <= t_abs) && (k_abs >= t_abs - 255);
        sv[nf][r] = valid ? s[r]*0.125f : -1e30f;
      }
    }
    float cm[4], alpha[4], rs[4];
    #pragma unroll
    for (int r=0;r<4;r++){
      cm[r] = fmaxf(fmaxf(sv[0][r],sv[1][r]), fmaxf(sv[2][r],sv[3][r]));
      #pragma unroll
      for (int off=1; off<16; off<<=1) cm[r] = fmaxf(cm[r], __shfl_xor(cm[r], off));
      const float mnew = fmaxf(mrow[r], cm[r]);
      alpha[r] = __expf(mrow[r] - mnew);
      mrow[r] = mnew;
      rs[r] = 0.f;
    }
    #pragma unroll
    for (int nf=0; nf<4; nf++){
      const int pcol = nf*16 + (ln & 15);
      #pragma unroll
      for (int r=0;r<4;r++){
        const float p = (sv[nf][r] <= -1e29f) ? 0.f : __expf(sv[nf][r] - mrow[r]);
        rs[r] += p;
        const int prow = (ln>>4)*4 + r;
        const int pb = (pcol>>3) ^ (prow & 7);
        Ps[w][prow*ATS + pb*8 + (pcol & 7)] = (short)f2bf(p);
      }
    }
    #pragma unroll
    for (int r=0;r<4;r++){
      #pragma unroll
      for (int off=1; off<16; off<<=1) rs[r] += __shfl_xor(rs[r], off);
      lrow[r] = lrow[r]*alpha[r] + rs[r];
      #pragma unroll
      for (int df=0; df<4; df++) oacc[df][r] *= alpha[r];
    }
    bf16x8 ap[2];
    #pragma unroll
    for (int ks=0; ks<2; ks++){
      const int prow = (ln & 15);
      const int b = (ks*4 + (ln>>4)) ^ (prow & 7);
      ap[ks] = *reinterpret_cast<const bf16x8*>(&Ps[w][prow*ATS + b*8]);
    }
    #pragma unroll
    for (int df=0; df<4; df++){
      const int vrow = df*16 + (ln & 15);
      #pragma unroll
      for (int ks=0; ks<2; ks++){
        const int b = (ks*4 + (ln>>4)) ^ ((vrow>>3) & 7);
        const bf16x8 bv = *reinterpret_cast<const bf16x8*>(&Vt[vrow*ATS + b*8]);
        oacc[df] = __builtin_amdgcn_mfma_f32_16x16x32_bf16(ap[ks], bv, oacc[df], 0, 0, 0);
      }
    }
    __syncthreads();
  }

  #pragma unroll
  for (int df=0; df<4; df++)
    #pragma unroll
    for (int r=0; r<4; r++){
      const int t = qt0 + qrow_lane + r;
      const int d = df*16 + (ln & 15);
      attn_out[(size_t)t*1024 + h*64 + d] = (short)f2bf(oacc[df][r] / lrow[r]);
    }
}

// ---------------- SSM scan as 16-tap convolution (compact drive) ------------
__global__ __launch_bounds__(256) void scan_kernel(const float* __restrict__ drive,
    const float* __restrict__ Aa, short* __restrict__ states)
{
  const int idx = blockIdx.x*256 + threadIdx.x;
  const int t = idx >> 7, s = idx & 127;
  const float a = Aa[s];
  float acc = 0.f, pw = 1.f;
  const int kmax = (t+1 < 16) ? (t+1) : 16;
  for (int k=0;k<kmax;k++){
    acc = fmaf(pw, drive[(size_t)(t-k)*128 + s], acc);
    pw *= a;
  }
  states[idx] = (short)f2bf(acc);
}

extern "C" void kernel_launch(void* const* d_in, const int* in_sizes, int n_in,
                              void* d_out, int out_size, void* d_ws, size_t ws_size,
                              hipStream_t stream)
{
  const float* x     = (const float*)d_in[0];
  const float* ln1_g = (const float*)d_in[1];
  const float* ln1_b = (const float*)d_in[2];
  const float* ln2_g = (const float*)d_in[3];
  const float* ln2_b = (const float*)d_in[4];
  const float* W_qkv = (const float*)d_in[5];
  const float* W_O   = (const float*)d_in[6];
  const float* b_O   = (const float*)d_in[7];
  const float* W_ug  = (const float*)d_in[8];
  const float* b_ug  = (const float*)d_in[9];
  const float* B_w   = (const float*)d_in[10];
  const float* A     = (const float*)d_in[11];
  const float* C_w   = (const float*)d_in[12];
  const float* W1    = (const float*)d_in[13];
  const float* b1    = (const float*)d_in[14];
  const float* W2    = (const float*)d_in[15];
  const float* b2    = (const float*)d_in[16];
  float* out = (float*)d_out;
  char* ws = (char*)d_ws;

  short* qkv_bf = (short*)(ws + 0);          // 24MB
  short* attn_bf= (short*)(ws + 25165824);   // 8MB
  short* xn_bf  = (short*)(ws + 33554432);   // 8MB (h aliases)
  short* g_bf   = (short*)(ws + 41943040);   // 8MB
  float* drive  = (float*)(ws + 50331648);   // 2MB
  short* st_bf  = (short*)(ws + 52428800);   // 1MB
  short* wT_qkv = (short*)(ws + 53542912);   // 6MB
  short* wT_o   = (short*)(ws + 59834368);   // 2MB
  short* wT_ug  = (short*)(ws + 61931520);   // 2.25MB
  short* wT_c   = (short*)(ws + 64290816);   // 0.25MB
  short* wT_1   = (short*)(ws + 64552960);   // 8MB
  short* wT_2   = (short*)(ws + 72941568);   // 8MB
  short* mid_bf = (short*)(ws + 0);          // 32MB alias (dead qkv+attn)
  short* h_bf   = xn_bf;

  static bool attr_done = false;
  if (!attr_done) {
    hipFuncSetAttribute((const void*)(gemm256<192,0>), hipFuncAttributeMaxDynamicSharedMemorySize, 114688);
    hipFuncSetAttribute((const void*)(gemm256<256,1>), hipFuncAttributeMaxDynamicSharedMemorySize, 131072);
    hipFuncSetAttribute((const void*)(gemm128<2,1>), hipFuncAttributeMaxDynamicSharedMemorySize, 49152);
    hipFuncSetAttribute((const void*)(gemm128<2,3>), hipFuncAttributeMaxDynamicSharedMemorySize, 49152);
    hipFuncSetAttribute((const void*)wo_comb, hipFuncAttributeMaxDynamicSharedMemorySize, 49152);
    attr_done = true;
  }

  // prep: all weight transposes + LN1 fused (13568 + 4096 blocks)
  prep_weights<<<17664, 256, 0, stream>>>(W_qkv, W_O, W_ug, B_w, C_w, W1, W2,
                                          x, ln1_g, ln1_b,
                                          wT_qkv, wT_o, wT_ug, wT_c, wT_1, wT_2,
                                          xn_bf);

  // qkv: 256x192 tiles -> grid (16,16) = 256 blocks, all CUs busy
  gemm256<192,0><<<dim3(16,16), 512, 114688, stream>>>(xn_bf, wT_qkv, nullptr, qkv_bf, 4096, 3072, 1024);
  attn_mfma<<<1024, 256, 0, stream>>>(qkv_bf, attn_bf);
  gemm128<2,1><<<dim3(9,64), 256, 49152, stream>>>(xn_bf, wT_ug, b_ug, g_bf, drive, 4096, 1152, 1024);
  scan_kernel<<<2048, 256, 0, stream>>>(drive, A, st_bf);
  wo_comb<<<dim3(8,64), 256, 49152, stream>>>(attn_bf, wT_o, st_bf, wT_c, b_O, x, g_bf, out);
  ln_bf16<<<4096, 256, 0, stream>>>(out, ln2_g, ln2_b, h_bf);
  gemm256<256,1><<<dim3(16,16), 512, 131072, stream>>>(h_bf, wT_1, b1, mid_bf, 4096, 4096, 1024);
  gemm128<2,3><<<dim3(8,64), 256, 49152, stream>>>(mid_bf, wT_2, b2, nullptr, out, 4096, 1024, 4096);
}